// Round 1
// baseline (771.286 us; speedup 1.0000x reference)
//
#include <hip/hip_runtime.h>
#include <hip/hip_bf16.h>

using bf16 = __hip_bfloat16;
typedef short s16x8 __attribute__((ext_vector_type(8)));
typedef float f32x4 __attribute__((ext_vector_type(4)));
typedef float f32x2 __attribute__((ext_vector_type(2)));

#define BSZ   8
#define NN    15135
#define FF    64
#define GG    73
#define HH    256
#define EE    242160
#define K1P   160                 // 137 padded to mult of 32
#define MREAL (BSZ * NN)          // 121080
#define MPAD  (946 * 128)         // 121088
#define HFC   512
#define NCHUNK 64
#define NCHUNKS ((NN + NCHUNK - 1) / NCHUNK)   // 237
#define SCANB  ((NN + 255) / 256)              // 60
// fp8 pre-scale: hw stored as e4m3(64*v); 1/64 folded into csr_norm & dinv
#define FP8_INV_SCALE 0.015625f

#define GLOAD_LDS16(gp, lp)                                                     \
    __builtin_amdgcn_global_load_lds(                                           \
        (const __attribute__((address_space(1))) void*)(gp),                    \
        (__attribute__((address_space(3))) void*)(lp), 16, 0, 0)

__device__ __forceinline__ float b2f(short s) {
    union { unsigned u; float f; } x;
    x.u = ((unsigned)(unsigned short)s) << 16;
    return x.f;
}

// decode 16 fp8 (e4m3) from a uint4 into f[0..15] via HW cvt
__device__ __forceinline__ void dec16(uint4 q, float* f) {
    f32x2 t;
    t = __builtin_amdgcn_cvt_pk_f32_fp8(q.x, false); f[0]  = t[0]; f[1]  = t[1];
    t = __builtin_amdgcn_cvt_pk_f32_fp8(q.x, true);  f[2]  = t[0]; f[3]  = t[1];
    t = __builtin_amdgcn_cvt_pk_f32_fp8(q.y, false); f[4]  = t[0]; f[5]  = t[1];
    t = __builtin_amdgcn_cvt_pk_f32_fp8(q.y, true);  f[6]  = t[0]; f[7]  = t[1];
    t = __builtin_amdgcn_cvt_pk_f32_fp8(q.z, false); f[8]  = t[0]; f[9]  = t[1];
    t = __builtin_amdgcn_cvt_pk_f32_fp8(q.z, true);  f[10] = t[0]; f[11] = t[1];
    t = __builtin_amdgcn_cvt_pk_f32_fp8(q.w, false); f[12] = t[0]; f[13] = t[1];
    t = __builtin_amdgcn_cvt_pk_f32_fp8(q.w, true);  f[14] = t[0]; f[15] = t[1];
}

__device__ __forceinline__ unsigned char enc8(float v) {
    int p = __builtin_amdgcn_cvt_pk_fp8_f32(v, v, 0, false);
    return (unsigned char)(p & 0xff);
}

// ---------------------------------------------------------------- degree hist
__global__ void k_deg(const int* __restrict__ col, int* __restrict__ cnt, int e) {
    int i = blockIdx.x * blockDim.x + threadIdx.x;
    if (i < e) atomicAdd(&cnt[col[i]], 1);
}

// --------------------------------------------------------- scan phase A
__global__ __launch_bounds__(256)
void k_scanA(const int* __restrict__ cnt, int* __restrict__ cursor,
             int* __restrict__ bsum) {
    __shared__ int ws[4];
    int i = blockIdx.x * 256 + threadIdx.x;
    int tid = threadIdx.x, lane = tid & 63, wid = tid >> 6;
    int v = (i < NN) ? cnt[i] : 0;
    int s = v;
    #pragma unroll
    for (int off = 1; off < 64; off <<= 1) {
        int t = __shfl_up(s, off);
        if (lane >= off) s += t;
    }
    if (lane == 63) ws[wid] = s;
    __syncthreads();
    int pre = 0;
    #pragma unroll
    for (int w = 0; w < 4; ++w) pre += (w < wid) ? ws[w] : 0;
    int incl = pre + s;
    if (i < NN) cursor[i] = incl;
    if (tid == 255) bsum[blockIdx.x] = incl;
}

// --------------------------------------------------------- scan phase B
__global__ __launch_bounds__(64)
void k_scanB(int* __restrict__ bsum, int* __restrict__ offs) {
    int t = threadIdx.x;
    int v = (t < SCANB) ? bsum[t] : 0;
    int s = v;
    #pragma unroll
    for (int off = 1; off < 64; off <<= 1) {
        int x = __shfl_up(s, off);
        if (t >= off) s += x;
    }
    if (t < SCANB) bsum[t] = s - v;      // exclusive
    if (t == 63) offs[NN] = s;           // grand total
}

// --------------------------------------------------------- scan phase C
__global__ __launch_bounds__(256)
void k_scanC(const int* __restrict__ cnt, int* __restrict__ cursor,
             const int* __restrict__ bsum, int* __restrict__ offs,
             float* __restrict__ dis, float* __restrict__ dinv) {
    int i = blockIdx.x * 256 + threadIdx.x;
    if (i >= NN) return;
    int v = cnt[i];
    int excl = cursor[i] - v + bsum[blockIdx.x];
    offs[i] = excl;
    cursor[i] = excl;
    float d = (float)(v + 1);
    dis[i]  = rsqrtf(d);
    dinv[i] = (1.0f / d) * FP8_INV_SCALE;
}

// ---------------------------------------------------------------- CSR fill
__global__ void k_csr(const int* __restrict__ row, const int* __restrict__ col,
                      int* __restrict__ cursor, const float* __restrict__ dis,
                      int* __restrict__ csr_row, float* __restrict__ csr_norm, int e) {
    int i = blockIdx.x * blockDim.x + threadIdx.x;
    if (i >= e) return;
    int r = row[i], c = col[i];
    int p = atomicAdd(&cursor[c], 1);
    csr_row[p]  = r;
    csr_norm[p] = dis[r] * dis[c] * FP8_INV_SCALE;
}

// --------------------------------------------------------- h0 = [x | pe | 0]
__global__ void k_prep_h0(const float* __restrict__ x, const float* __restrict__ gl,
                          bf16* __restrict__ h0) {
    int idx = blockIdx.x * blockDim.x + threadIdx.x;
    if (idx >= MREAL * (K1P / 8)) return;
    int m = idx / (K1P / 8);
    int q = idx - m * (K1P / 8);
    int j0 = q * 8;
    int n = m % NN;
    s16x8 o;
    #pragma unroll
    for (int k = 0; k < 8; ++k) {
        int j = j0 + k;
        float val;
        if (j < FF) val = x[(size_t)m * FF + j];
        else if (j < FF + GG) val = gl[(size_t)n * GG + (j - FF)];
        else val = 0.f;
        o[k] = (short)__bfloat16_as_ushort(__float2bfloat16(val));
    }
    *(s16x8*)&h0[(size_t)m * K1P + j0] = o;
}

// ---------------------------------------------- W [K,256] f32 -> WT [256,Kp] bf16
__global__ void k_prep_w(const float* __restrict__ W, bf16* __restrict__ WT,
                         int K, int Kpad) {
    int idx = blockIdx.x * blockDim.x + threadIdx.x;
    if (idx >= 256 * Kpad) return;
    int nn = idx / Kpad, kk = idx - nn * Kpad;
    WT[idx] = __float2bfloat16(kk < K ? W[(size_t)kk * 256 + nn] : 0.f);
}

// ---------------------------------------------------------------- MFMA GEMM
// m97 structure: global_load_lds width=16, unpadded [128][32] LDS tiles.
// C_perm (fp8, x64) [(n*8+b)*256 + col] = 64 * sum_k A[(b*NN+n)][k] * WT[col][k]
#define BK 32
template <int K>
__global__ __launch_bounds__(256)
void k_gemm(const bf16* __restrict__ A, const bf16* __restrict__ BT,
            unsigned char* __restrict__ C) {
    __shared__ __align__(16) short As[128 * BK];
    __shared__ __align__(16) short Bs[128 * BK];
    const int tid  = threadIdx.x;
    const int bm   = blockIdx.x * 128;
    const int bn   = blockIdx.y * 128;
    const int lane = tid & 63, wave = tid >> 6;
    const int wm   = (wave >> 1) * 64, wn = (wave & 1) * 64;
    const int fr   = lane & 15, quad = lane >> 4;
    const int r    = tid >> 2;           // 0..63
    const int c    = (tid & 3) * 8;      // shorts: 0,8,16,24

    const bf16* Ap0 = A  + (size_t)(bm + r) * K + c;
    const bf16* Ap1 = Ap0 + (size_t)64 * K;
    const bf16* Bp0 = BT + (size_t)(bn + r) * K + c;
    const bf16* Bp1 = Bp0 + (size_t)64 * K;
    short* AsT0 = As + tid * 8;          // byte offset tid*16 (rows 0..63)
    short* AsT1 = As + 2048 + tid * 8;   // rows 64..127
    short* BsT0 = Bs + tid * 8;
    short* BsT1 = Bs + 2048 + tid * 8;

    f32x4 acc[4][4] = {};

    for (int k0 = 0; k0 < K; k0 += BK) {
        GLOAD_LDS16(Ap0 + k0, AsT0);
        GLOAD_LDS16(Ap1 + k0, AsT1);
        GLOAD_LDS16(Bp0 + k0, BsT0);
        GLOAD_LDS16(Bp1 + k0, BsT1);
        __syncthreads();
        s16x8 af[4], bfv[4];
        #pragma unroll
        for (int i = 0; i < 4; ++i)
            af[i] = *(const s16x8*)&As[(wm + i * 16 + fr) * BK + quad * 8];
        #pragma unroll
        for (int j = 0; j < 4; ++j)
            bfv[j] = *(const s16x8*)&Bs[(wn + j * 16 + fr) * BK + quad * 8];
        #pragma unroll
        for (int i = 0; i < 4; ++i)
            #pragma unroll
            for (int j = 0; j < 4; ++j)
                acc[i][j] = __builtin_amdgcn_mfma_f32_16x16x32_bf16(
                    af[i], bfv[j], acc[i][j], 0, 0, 0);
        __syncthreads();
    }

    // epilogue: store permuted fp8 [(n*8+b)][256], value x64
    #pragma unroll
    for (int i = 0; i < 4; ++i) {
        int rbase = bm + wm + i * 16 + quad * 4;
        #pragma unroll
        for (int rr = 0; rr < 4; ++rr) {
            int row = rbase + rr;
            if (row >= MREAL) continue;
            int b = row / NN;
            int n = row - b * NN;
            size_t co = ((size_t)n * 8 + b) * 256;
            #pragma unroll
            for (int j = 0; j < 4; ++j) {
                int colx = bn + wn + j * 16 + fr;
                C[co + colx] = enc8(acc[i][j][rr] * 64.f);
            }
        }
    }
}

// ------------------------------------------------------- aggregate + elu + fc
// hw fp8 permuted [(n*8+b)][256] (x64); hout bf16 [b*NN+n][256].
// 128 threads: b = tid>>4, cols [c16,c16+16). Neighbor list staged in LDS,
// row gathers unrolled x8 for deep MLP (latency-bound fix).
#define ECH 96
__global__ __launch_bounds__(128)
void k_agg(const unsigned char* __restrict__ hw, bf16* __restrict__ hout,
           const int* __restrict__ offs, const int* __restrict__ csr_row,
           const float* __restrict__ csr_norm, const float* __restrict__ dinv,
           const float* __restrict__ bias, const float* __restrict__ fcW,
           float* __restrict__ g, int writeH) {
    const int v   = blockIdx.x;
    const int tid = threadIdx.x;
    const int b   = tid >> 4;
    const int c16 = (tid & 15) * 16;
    const int boff = b * 256 + c16;
    const int beg = offs[v], end = offs[v + 1];
    const float di = dinv[v];   // includes 1/64

    __shared__ int   sIdx[ECH];
    __shared__ float sNrm[ECH];

    float acc[16];
    {
        uint4 q = *(const uint4*)(hw + (size_t)v * 2048 + boff);
        float f[16]; dec16(q, f);
        #pragma unroll
        for (int k = 0; k < 16; ++k) acc[k] = di * f[k];
    }

    for (int base = beg; base < end; base += ECH) {
        int cnt = end - base; if (cnt > ECH) cnt = ECH;
        __syncthreads();
        if (tid < cnt) {
            sIdx[tid] = csr_row[base + tid];
            sNrm[tid] = csr_norm[base + tid];
        }
        __syncthreads();
        int e = 0;
        for (; e + 8 <= cnt; e += 8) {
            uint4 q[8];
            #pragma unroll
            for (int u = 0; u < 8; ++u)
                q[u] = *(const uint4*)(hw + (size_t)sIdx[e + u] * 2048 + boff);
            #pragma unroll
            for (int u = 0; u < 8; ++u) {
                float m = sNrm[e + u];
                float f[16]; dec16(q[u], f);
                #pragma unroll
                for (int k = 0; k < 16; ++k) acc[k] += m * f[k];
            }
        }
        for (; e < cnt; ++e) {
            float m = sNrm[e];
            uint4 q0 = *(const uint4*)(hw + (size_t)sIdx[e] * 2048 + boff);
            float f[16]; dec16(q0, f);
            #pragma unroll
            for (int k = 0; k < 16; ++k) acc[k] += m * f[k];
        }
    }

    float p = 0.f;
    s16x8 ob0, ob1;
    #pragma unroll
    for (int k = 0; k < 16; ++k) {
        float hv = acc[k] + bias[c16 + k];
        hv = hv > 0.f ? hv : expm1f(hv);
        if (k < 8) ob0[k] = (short)__bfloat16_as_ushort(__float2bfloat16(hv));
        else       ob1[k - 8] = (short)__bfloat16_as_ushort(__float2bfloat16(hv));
        p += hv * fcW[3 * (c16 + k)];
    }
    if (writeH) {
        size_t ho = ((size_t)b * NN + v) * 256 + c16;
        *(s16x8*)&hout[ho]     = ob0;
        *(s16x8*)&hout[ho + 8] = ob1;
    }

    #pragma unroll
    for (int off = 8; off; off >>= 1) p += __shfl_xor(p, off, 16);
    __shared__ float gs[8];
    if ((tid & 15) == 0) gs[b] = p;
    __syncthreads();
    if (tid < 8) g[(size_t)tid * NN + v] += gs[tid];
}

// ------------------------------------------------------------ lin1 partials
__global__ __launch_bounds__(256)
void k_lin1(const float* __restrict__ g, const float* __restrict__ fcb,
            const float* __restrict__ W, float* __restrict__ zpart) {
    const int ny = blockIdx.x;
    const int n0 = ny * NCHUNK;
    const int cnt = min(NCHUNK, NN - n0);
    const int tid = threadIdx.x;
    __shared__ float sg[8][NCHUNK];
    float fb = fcb[0];
    for (int idx = tid; idx < 8 * NCHUNK; idx += 256) {
        int b = idx / NCHUNK, nn = idx - b * NCHUNK;
        sg[b][nn] = (nn < cnt) ? (g[(size_t)b * NN + n0 + nn] + fb) : 0.f;
    }
    __syncthreads();
    float2 acc[8] = {};
    for (int nn = 0; nn < cnt; ++nn) {
        float2 w = *(const float2*)&W[(size_t)(n0 + nn) * HFC + tid * 2];
        #pragma unroll
        for (int b = 0; b < 8; ++b) {
            float gv = sg[b][nn];
            acc[b].x += gv * w.x;
            acc[b].y += gv * w.y;
        }
    }
    #pragma unroll
    for (int b = 0; b < 8; ++b)
        *(float2*)&zpart[(size_t)ny * 4096 + b * 512 + tid * 2] = acc[b];
}

__global__ __launch_bounds__(256)
void k_lin1red(const float* __restrict__ zpart, float* __restrict__ zacc) {
    int t = blockIdx.x * 256 + threadIdx.x;   // 0..4095
    float s = 0.f;
    for (int c = 0; c < NCHUNKS; ++c) s += zpart[(size_t)c * 4096 + t];
    zacc[t] = s;
}

// --------------------------------------------------- lin2 + log_softmax (tiny)
__global__ __launch_bounds__(512)
void k_final(const float* __restrict__ zacc, const float* __restrict__ l1b,
             const float* __restrict__ W2, const float* __restrict__ l2b,
             float* __restrict__ out) {
    __shared__ float r0[512], r1[512];
    int t = threadIdx.x;
    for (int b = 0; b < 8; ++b) {
        float zv = zacc[b * HFC + t] + l1b[t];
        zv = zv > 0.f ? zv : expm1f(zv);
        r0[t] = zv * W2[t * 2 + 0];
        r1[t] = zv * W2[t * 2 + 1];
        __syncthreads();
        for (int s = 256; s; s >>= 1) {
            if (t < s) { r0[t] += r0[t + s]; r1[t] += r1[t + s]; }
            __syncthreads();
        }
        if (t == 0) {
            float o0 = r0[0] + l2b[0], o1 = r1[0] + l2b[1];
            float m = fmaxf(o0, o1);
            float lse = m + logf(expf(o0 - m) + expf(o1 - m));
            out[b * 2 + 0] = o0 - lse;
            out[b * 2 + 1] = o1 - lse;
        }
        __syncthreads();
    }
}

// ---------------------------------------------------------------- launcher
extern "C" void kernel_launch(void* const* d_in, const int* in_sizes, int n_in,
                              void* d_out, int out_size, void* d_ws, size_t ws_size,
                              hipStream_t stream) {
    const float* x    = (const float*)d_in[0];
    const int*   eidx = (const int*)d_in[2];      // [0..E) = row, [E..2E) = col
    const float* gl   = (const float*)d_in[3];
    const float* W1   = (const float*)d_in[4];
    const float* b1   = (const float*)d_in[5];
    const float* W2   = (const float*)d_in[6];
    const float* b2   = (const float*)d_in[7];
    const float* W3   = (const float*)d_in[8];
    const float* b3   = (const float*)d_in[9];
    const float* fcW  = (const float*)d_in[10];
    const float* fcb  = (const float*)d_in[11];
    const float* l1W  = (const float*)d_in[12];
    const float* l1b  = (const float*)d_in[13];
    const float* l2W  = (const float*)d_in[14];
    const float* l2b  = (const float*)d_in[15];
    float* out = (float*)d_out;

    size_t off = 0;
    auto alloc = [&](size_t bytes) {
        void* p = (char*)d_ws + off;
        off += (bytes + 255) & ~(size_t)255;
        return p;
    };
    bf16* bufA          = (bf16*)alloc((size_t)MPAD * 256 * 2);          // 62 MB
    unsigned char* bufC = (unsigned char*)alloc((size_t)MPAD * 256);     // 31 MB
    bf16* W1T      = (bf16*)alloc(256 * K1P * 2);
    bf16* W2T      = (bf16*)alloc(256 * 256 * 2);
    bf16* W3T      = (bf16*)alloc(256 * 256 * 2);
    int*  deg_cnt  = (int*)alloc(NN * 4);
    int*  offs     = (int*)alloc((NN + 1) * 4);
    int*  cursor   = (int*)alloc(NN * 4);
    int*  bsum     = (int*)alloc(SCANB * 4);
    float* dis     = (float*)alloc(NN * 4);
    float* dinv    = (float*)alloc(NN * 4);
    int*  csr_row  = (int*)alloc((size_t)EE * 4);
    float* csr_nrm = (float*)alloc((size_t)EE * 4);
    float* g       = (float*)alloc((size_t)BSZ * NN * 4);

    // zpart/zacc alias bufC: dead after the last k_agg
    float* zpart = (float*)bufC;                              // 3.9 MB
    float* zacc  = (float*)(bufC + (8 << 20));                // 16 KB

    hipMemsetAsync(deg_cnt, 0, NN * 4, stream);
    hipMemsetAsync(g, 0, (size_t)BSZ * NN * 4, stream);

    const int* erow = eidx;
    const int* ecol = eidx + EE;

    k_deg<<<(EE + 255) / 256, 256, 0, stream>>>(ecol, deg_cnt, EE);
    k_scanA<<<SCANB, 256, 0, stream>>>(deg_cnt, cursor, bsum);
    k_scanB<<<1, 64, 0, stream>>>(bsum, offs);
    k_scanC<<<SCANB, 256, 0, stream>>>(deg_cnt, cursor, bsum, offs, dis, dinv);
    k_csr<<<(EE + 255) / 256, 256, 0, stream>>>(erow, ecol, cursor, dis,
                                                csr_row, csr_nrm, EE);

    k_prep_h0<<<(MREAL * (K1P / 8) + 255) / 256, 256, 0, stream>>>(x, gl, bufA);
    k_prep_w<<<(256 * K1P + 255) / 256, 256, 0, stream>>>(W1, W1T, FF + GG, K1P);
    k_prep_w<<<(256 * 256 + 255) / 256, 256, 0, stream>>>(W2, W2T, 256, 256);
    k_prep_w<<<(256 * 256 + 255) / 256, 256, 0, stream>>>(W3, W3T, 256, 256);

    dim3 ggrid(MPAD / 128, 2);

    // layer 1
    k_gemm<K1P><<<ggrid, 256, 0, stream>>>(bufA, W1T, bufC);
    k_agg<<<NN, 128, 0, stream>>>(bufC, bufA, offs, csr_row, csr_nrm, dinv,
                                  b1, fcW + 0, g, 1);
    // layer 2
    k_gemm<256><<<ggrid, 256, 0, stream>>>(bufA, W2T, bufC);
    k_agg<<<NN, 128, 0, stream>>>(bufC, bufA, offs, csr_row, csr_nrm, dinv,
                                  b2, fcW + 1, g, 1);
    // layer 3 (h3 not materialized; only fc contribution)
    k_gemm<256><<<ggrid, 256, 0, stream>>>(bufA, W3T, bufC);
    k_agg<<<NN, 128, 0, stream>>>(bufC, bufA, offs, csr_row, csr_nrm, dinv,
                                  b3, fcW + 2, g, 0);

    k_lin1<<<NCHUNKS, 256, 0, stream>>>(g, fcb, l1W, zpart);
    k_lin1red<<<16, 256, 0, stream>>>(zpart, zacc);
    k_final<<<1, 512, 0, stream>>>(zacc, l1b, l2W, l2b, out);
}

// Round 2
// 627.507 us; speedup vs baseline: 1.2291x; 1.2291x over previous
//
#include <hip/hip_runtime.h>
#include <hip/hip_bf16.h>

using bf16 = __hip_bfloat16;
typedef short s16x8 __attribute__((ext_vector_type(8)));
typedef short s16x4 __attribute__((ext_vector_type(4)));
typedef float f32x4 __attribute__((ext_vector_type(4)));
typedef float f32x2 __attribute__((ext_vector_type(2)));

#define BSZ   8
#define NN    15135
#define FF    64
#define GG    73
#define HH    256
#define EE    242160
#define K1P   160                 // 137 padded to mult of 32
#define MREAL (BSZ * NN)          // 121080
#define MPAD  (946 * 128)         // 121088
#define HFC   512
#define NCHUNK 64
#define NCHUNKS ((NN + NCHUNK - 1) / NCHUNK)   // 237
#define SCANB  ((NN + 255) / 256)              // 60
// fp8 pre-scale: hw stored as e4m3(64*v); 1/64 folded into csr_norm & dinv
#define FP8_INV_SCALE 0.015625f

#define GLOAD_LDS16(gp, lp)                                                     \
    __builtin_amdgcn_global_load_lds(                                           \
        (const __attribute__((address_space(1))) void*)(gp),                    \
        (__attribute__((address_space(3))) void*)(lp), 16, 0, 0)

__device__ __forceinline__ float b2f(short s) {
    union { unsigned u; float f; } x;
    x.u = ((unsigned)(unsigned short)s) << 16;
    return x.f;
}

__device__ __forceinline__ unsigned char enc8(float v) {
    int p = __builtin_amdgcn_cvt_pk_fp8_f32(v, v, 0, false);
    return (unsigned char)(p & 0xff);
}

// ---------------------------------------------------------------- degree hist
__global__ void k_deg(const int* __restrict__ col, int* __restrict__ cnt, int e) {
    int i = blockIdx.x * blockDim.x + threadIdx.x;
    if (i < e) atomicAdd(&cnt[col[i]], 1);
}

// --------------------------------------------------------- scan phase A
__global__ __launch_bounds__(256)
void k_scanA(const int* __restrict__ cnt, int* __restrict__ cursor,
             int* __restrict__ bsum) {
    __shared__ int ws[4];
    int i = blockIdx.x * 256 + threadIdx.x;
    int tid = threadIdx.x, lane = tid & 63, wid = tid >> 6;
    int v = (i < NN) ? cnt[i] : 0;
    int s = v;
    #pragma unroll
    for (int off = 1; off < 64; off <<= 1) {
        int t = __shfl_up(s, off);
        if (lane >= off) s += t;
    }
    if (lane == 63) ws[wid] = s;
    __syncthreads();
    int pre = 0;
    #pragma unroll
    for (int w = 0; w < 4; ++w) pre += (w < wid) ? ws[w] : 0;
    int incl = pre + s;
    if (i < NN) cursor[i] = incl;
    if (tid == 255) bsum[blockIdx.x] = incl;
}

// --------------------------------------------------------- scan phase B
__global__ __launch_bounds__(64)
void k_scanB(int* __restrict__ bsum, int* __restrict__ offs) {
    int t = threadIdx.x;
    int v = (t < SCANB) ? bsum[t] : 0;
    int s = v;
    #pragma unroll
    for (int off = 1; off < 64; off <<= 1) {
        int x = __shfl_up(s, off);
        if (t >= off) s += x;
    }
    if (t < SCANB) bsum[t] = s - v;      // exclusive
    if (t == 63) offs[NN] = s;           // grand total
}

// --------------------------------------------------------- scan phase C
__global__ __launch_bounds__(256)
void k_scanC(const int* __restrict__ cnt, int* __restrict__ cursor,
             const int* __restrict__ bsum, int* __restrict__ offs,
             float* __restrict__ dis, float* __restrict__ dinv) {
    int i = blockIdx.x * 256 + threadIdx.x;
    if (i >= NN) return;
    int v = cnt[i];
    int excl = cursor[i] - v + bsum[blockIdx.x];
    offs[i] = excl;
    cursor[i] = excl;
    float d = (float)(v + 1);
    dis[i]  = rsqrtf(d);
    dinv[i] = (1.0f / d) * FP8_INV_SCALE;
}

// ---------------------------------------------------------------- CSR fill
__global__ void k_csr(const int* __restrict__ row, const int* __restrict__ col,
                      int* __restrict__ cursor, const float* __restrict__ dis,
                      int* __restrict__ csr_row, float* __restrict__ csr_norm, int e) {
    int i = blockIdx.x * blockDim.x + threadIdx.x;
    if (i >= e) return;
    int r = row[i], c = col[i];
    int p = atomicAdd(&cursor[c], 1);
    csr_row[p]  = r;
    csr_norm[p] = dis[r] * dis[c] * FP8_INV_SCALE;
}

// --------------------------------------------------------- h0 = [x | pe | 0]
__global__ void k_prep_h0(const float* __restrict__ x, const float* __restrict__ gl,
                          bf16* __restrict__ h0) {
    int idx = blockIdx.x * blockDim.x + threadIdx.x;
    if (idx >= MREAL * (K1P / 8)) return;
    int m = idx / (K1P / 8);
    int q = idx - m * (K1P / 8);
    int j0 = q * 8;
    int n = m % NN;
    s16x8 o;
    #pragma unroll
    for (int k = 0; k < 8; ++k) {
        int j = j0 + k;
        float val;
        if (j < FF) val = x[(size_t)m * FF + j];
        else if (j < FF + GG) val = gl[(size_t)n * GG + (j - FF)];
        else val = 0.f;
        o[k] = (short)__bfloat16_as_ushort(__float2bfloat16(val));
    }
    *(s16x8*)&h0[(size_t)m * K1P + j0] = o;
}

// ---------------------------------------------- W [K,256] f32 -> WT [256,Kp] bf16
__global__ void k_prep_w(const float* __restrict__ W, bf16* __restrict__ WT,
                         int K, int Kpad) {
    int idx = blockIdx.x * blockDim.x + threadIdx.x;
    if (idx >= 256 * Kpad) return;
    int nn = idx / Kpad, kk = idx - nn * Kpad;
    WT[idx] = __float2bfloat16(kk < K ? W[(size_t)kk * 256 + nn] : 0.f);
}

// ---------------------------------------------------------------- MFMA GEMM
// m97 structure: global_load_lds width=16, unpadded [128][32] LDS tiles.
// C (fp8, x64): [row][256] with row = b*NN+n  (per-batch planes, XCD-local agg)
#define BK 32
template <int K>
__global__ __launch_bounds__(256)
void k_gemm(const bf16* __restrict__ A, const bf16* __restrict__ BT,
            unsigned char* __restrict__ C) {
    __shared__ __align__(16) short As[128 * BK];
    __shared__ __align__(16) short Bs[128 * BK];
    const int tid  = threadIdx.x;
    const int bm   = blockIdx.x * 128;
    const int bn   = blockIdx.y * 128;
    const int lane = tid & 63, wave = tid >> 6;
    const int wm   = (wave >> 1) * 64, wn = (wave & 1) * 64;
    const int fr   = lane & 15, quad = lane >> 4;
    const int r    = tid >> 2;           // 0..63
    const int c    = (tid & 3) * 8;      // shorts: 0,8,16,24

    const bf16* Ap0 = A  + (size_t)(bm + r) * K + c;
    const bf16* Ap1 = Ap0 + (size_t)64 * K;
    const bf16* Bp0 = BT + (size_t)(bn + r) * K + c;
    const bf16* Bp1 = Bp0 + (size_t)64 * K;
    short* AsT0 = As + tid * 8;          // byte offset tid*16 (rows 0..63)
    short* AsT1 = As + 2048 + tid * 8;   // rows 64..127
    short* BsT0 = Bs + tid * 8;
    short* BsT1 = Bs + 2048 + tid * 8;

    f32x4 acc[4][4] = {};

    for (int k0 = 0; k0 < K; k0 += BK) {
        GLOAD_LDS16(Ap0 + k0, AsT0);
        GLOAD_LDS16(Ap1 + k0, AsT1);
        GLOAD_LDS16(Bp0 + k0, BsT0);
        GLOAD_LDS16(Bp1 + k0, BsT1);
        __syncthreads();
        s16x8 af[4], bfv[4];
        #pragma unroll
        for (int i = 0; i < 4; ++i)
            af[i] = *(const s16x8*)&As[(wm + i * 16 + fr) * BK + quad * 8];
        #pragma unroll
        for (int j = 0; j < 4; ++j)
            bfv[j] = *(const s16x8*)&Bs[(wn + j * 16 + fr) * BK + quad * 8];
        #pragma unroll
        for (int i = 0; i < 4; ++i)
            #pragma unroll
            for (int j = 0; j < 4; ++j)
                acc[i][j] = __builtin_amdgcn_mfma_f32_16x16x32_bf16(
                    af[i], bfv[j], acc[i][j], 0, 0, 0);
        __syncthreads();
    }

    // epilogue: store fp8 [row][256], value x64 (row = b*NN+n directly)
    #pragma unroll
    for (int i = 0; i < 4; ++i) {
        int rbase = bm + wm + i * 16 + quad * 4;
        #pragma unroll
        for (int rr = 0; rr < 4; ++rr) {
            int row = rbase + rr;
            if (row >= MREAL) continue;
            size_t co = (size_t)row * 256;
            #pragma unroll
            for (int j = 0; j < 4; ++j) {
                int colx = bn + wn + j * 16 + fr;
                C[co + colx] = enc8(acc[i][j][rr] * 64.f);
            }
        }
    }
}

// ------------------------------------------------------- aggregate + elu + fc
// hw fp8 [b*NN+n][256] (x64); hout bf16 [b*NN+n][256].
// Batch-partitioned for XCD L2 residency: blockIdx.x & 7 = batch (default
// dispatch maps blockIdx%8 -> XCD; each batch plane is 3.87 MB < 4 MB L2).
// 256 threads = 4 independent waves, one node per wave, no barriers.
// Per edge: wave reads one 256 B row (64 lanes x dword), csr entries are
// lane-distributed and broadcast via __shfl. 8-deep gather unroll.
#define AGG_GRP 512                       // node groups per batch
#define AGG_STRIDE (AGG_GRP * 4)          // 2048 waves per batch
__global__ __launch_bounds__(256)
void k_agg(const unsigned char* __restrict__ hw, bf16* __restrict__ hout,
           const int* __restrict__ offs, const int* __restrict__ csr_row,
           const float* __restrict__ csr_norm, const float* __restrict__ dinv,
           const float* __restrict__ bias, const float* __restrict__ fcW,
           float* __restrict__ g, int writeH) {
    const int b    = blockIdx.x & 7;
    const int grp  = blockIdx.x >> 3;          // 0..AGG_GRP-1
    const int wid  = threadIdx.x >> 6;         // 0..3
    const int lane = threadIdx.x & 63;
    const int wv   = grp * 4 + wid;            // 0..AGG_STRIDE-1
    const int c4   = lane * 4;

    const unsigned char* hwb = hw + (size_t)b * NN * 256;

    float bias4[4], fw4[4];
    #pragma unroll
    for (int k = 0; k < 4; ++k) {
        bias4[k] = bias[c4 + k];
        fw4[k]   = fcW[3 * (c4 + k)];
    }

    for (int v = wv; v < NN; v += AGG_STRIDE) {
        const int beg = offs[v], end = offs[v + 1];
        const float di = dinv[v];
        float acc[4];
        {
            unsigned q = *(const unsigned*)(hwb + (size_t)v * 256 + c4);
            f32x2 t0 = __builtin_amdgcn_cvt_pk_f32_fp8(q, false);
            f32x2 t1 = __builtin_amdgcn_cvt_pk_f32_fp8(q, true);
            acc[0] = di * t0[0]; acc[1] = di * t0[1];
            acc[2] = di * t1[0]; acc[3] = di * t1[1];
        }
        for (int base = beg; base < end; base += 64) {
            int cnt = min(64, end - base);
            int  ridx = 0; float rnrm = 0.f;
            if (lane < cnt) {
                ridx = csr_row[base + lane];
                rnrm = csr_norm[base + lane];
            }
            int e = 0;
            for (; e + 8 <= cnt; e += 8) {
                int idx[8];
                #pragma unroll
                for (int u = 0; u < 8; ++u) idx[u] = __shfl(ridx, e + u);
                unsigned q[8];
                #pragma unroll
                for (int u = 0; u < 8; ++u)
                    q[u] = *(const unsigned*)(hwb + (size_t)idx[u] * 256 + c4);
                #pragma unroll
                for (int u = 0; u < 8; ++u) {
                    float m = __shfl(rnrm, e + u);
                    f32x2 t0 = __builtin_amdgcn_cvt_pk_f32_fp8(q[u], false);
                    f32x2 t1 = __builtin_amdgcn_cvt_pk_f32_fp8(q[u], true);
                    acc[0] += m * t0[0]; acc[1] += m * t0[1];
                    acc[2] += m * t1[0]; acc[3] += m * t1[1];
                }
            }
            for (; e < cnt; ++e) {
                int ii  = __shfl(ridx, e);
                float m = __shfl(rnrm, e);
                unsigned q = *(const unsigned*)(hwb + (size_t)ii * 256 + c4);
                f32x2 t0 = __builtin_amdgcn_cvt_pk_f32_fp8(q, false);
                f32x2 t1 = __builtin_amdgcn_cvt_pk_f32_fp8(q, true);
                acc[0] += m * t0[0]; acc[1] += m * t0[1];
                acc[2] += m * t1[0]; acc[3] += m * t1[1];
            }
        }

        float p = 0.f;
        s16x4 o4;
        #pragma unroll
        for (int k = 0; k < 4; ++k) {
            float hv = acc[k] + bias4[k];
            hv = hv > 0.f ? hv : expm1f(hv);
            o4[k] = (short)__bfloat16_as_ushort(__float2bfloat16(hv));
            p += hv * fw4[k];
        }
        if (writeH)
            *(s16x4*)&hout[((size_t)b * NN + v) * 256 + c4] = o4;

        #pragma unroll
        for (int off = 32; off; off >>= 1) p += __shfl_xor(p, off);
        if (lane == 0) g[(size_t)b * NN + v] += p;
    }
}

// ------------------------------------------------------------ lin1 partials
__global__ __launch_bounds__(256)
void k_lin1(const float* __restrict__ g, const float* __restrict__ fcb,
            const float* __restrict__ W, float* __restrict__ zpart) {
    const int ny = blockIdx.x;
    const int n0 = ny * NCHUNK;
    const int cnt = min(NCHUNK, NN - n0);
    const int tid = threadIdx.x;
    __shared__ float sg[8][NCHUNK];
    float fb = fcb[0];
    for (int idx = tid; idx < 8 * NCHUNK; idx += 256) {
        int b = idx / NCHUNK, nn = idx - b * NCHUNK;
        sg[b][nn] = (nn < cnt) ? (g[(size_t)b * NN + n0 + nn] + fb) : 0.f;
    }
    __syncthreads();
    float2 acc[8] = {};
    for (int nn = 0; nn < cnt; ++nn) {
        float2 w = *(const float2*)&W[(size_t)(n0 + nn) * HFC + tid * 2];
        #pragma unroll
        for (int b = 0; b < 8; ++b) {
            float gv = sg[b][nn];
            acc[b].x += gv * w.x;
            acc[b].y += gv * w.y;
        }
    }
    #pragma unroll
    for (int b = 0; b < 8; ++b)
        *(float2*)&zpart[(size_t)ny * 4096 + b * 512 + tid * 2] = acc[b];
}

__global__ __launch_bounds__(256)
void k_lin1red(const float* __restrict__ zpart, float* __restrict__ zacc) {
    int t = blockIdx.x * 256 + threadIdx.x;   // 0..4095
    float s = 0.f;
    for (int c = 0; c < NCHUNKS; ++c) s += zpart[(size_t)c * 4096 + t];
    zacc[t] = s;
}

// --------------------------------------------------- lin2 + log_softmax (tiny)
__global__ __launch_bounds__(512)
void k_final(const float* __restrict__ zacc, const float* __restrict__ l1b,
             const float* __restrict__ W2, const float* __restrict__ l2b,
             float* __restrict__ out) {
    __shared__ float r0[512], r1[512];
    int t = threadIdx.x;
    for (int b = 0; b < 8; ++b) {
        float zv = zacc[b * HFC + t] + l1b[t];
        zv = zv > 0.f ? zv : expm1f(zv);
        r0[t] = zv * W2[t * 2 + 0];
        r1[t] = zv * W2[t * 2 + 1];
        __syncthreads();
        for (int s = 256; s; s >>= 1) {
            if (t < s) { r0[t] += r0[t + s]; r1[t] += r1[t + s]; }
            __syncthreads();
        }
        if (t == 0) {
            float o0 = r0[0] + l2b[0], o1 = r1[0] + l2b[1];
            float m = fmaxf(o0, o1);
            float lse = m + logf(expf(o0 - m) + expf(o1 - m));
            out[b * 2 + 0] = o0 - lse;
            out[b * 2 + 1] = o1 - lse;
        }
        __syncthreads();
    }
}

// ---------------------------------------------------------------- launcher
extern "C" void kernel_launch(void* const* d_in, const int* in_sizes, int n_in,
                              void* d_out, int out_size, void* d_ws, size_t ws_size,
                              hipStream_t stream) {
    const float* x    = (const float*)d_in[0];
    const int*   eidx = (const int*)d_in[2];      // [0..E) = row, [E..2E) = col
    const float* gl   = (const float*)d_in[3];
    const float* W1   = (const float*)d_in[4];
    const float* b1   = (const float*)d_in[5];
    const float* W2   = (const float*)d_in[6];
    const float* b2   = (const float*)d_in[7];
    const float* W3   = (const float*)d_in[8];
    const float* b3   = (const float*)d_in[9];
    const float* fcW  = (const float*)d_in[10];
    const float* fcb  = (const float*)d_in[11];
    const float* l1W  = (const float*)d_in[12];
    const float* l1b  = (const float*)d_in[13];
    const float* l2W  = (const float*)d_in[14];
    const float* l2b  = (const float*)d_in[15];
    float* out = (float*)d_out;

    size_t off = 0;
    auto alloc = [&](size_t bytes) {
        void* p = (char*)d_ws + off;
        off += (bytes + 255) & ~(size_t)255;
        return p;
    };
    bf16* bufA          = (bf16*)alloc((size_t)MPAD * 256 * 2);          // 62 MB
    unsigned char* bufC = (unsigned char*)alloc((size_t)MPAD * 256);     // 31 MB
    bf16* W1T      = (bf16*)alloc(256 * K1P * 2);
    bf16* W2T      = (bf16*)alloc(256 * 256 * 2);
    bf16* W3T      = (bf16*)alloc(256 * 256 * 2);
    int*  deg_cnt  = (int*)alloc(NN * 4);
    int*  offs     = (int*)alloc((NN + 1) * 4);
    int*  cursor   = (int*)alloc(NN * 4);
    int*  bsum     = (int*)alloc(SCANB * 4);
    float* dis     = (float*)alloc(NN * 4);
    float* dinv    = (float*)alloc(NN * 4);
    int*  csr_row  = (int*)alloc((size_t)EE * 4);
    float* csr_nrm = (float*)alloc((size_t)EE * 4);
    float* g       = (float*)alloc((size_t)BSZ * NN * 4);

    // zpart/zacc alias bufC: dead after the last k_agg
    float* zpart = (float*)bufC;                              // 3.9 MB
    float* zacc  = (float*)(bufC + (8 << 20));                // 16 KB

    hipMemsetAsync(deg_cnt, 0, NN * 4, stream);
    hipMemsetAsync(g, 0, (size_t)BSZ * NN * 4, stream);

    const int* erow = eidx;
    const int* ecol = eidx + EE;

    k_deg<<<(EE + 255) / 256, 256, 0, stream>>>(ecol, deg_cnt, EE);
    k_scanA<<<SCANB, 256, 0, stream>>>(deg_cnt, cursor, bsum);
    k_scanB<<<1, 64, 0, stream>>>(bsum, offs);
    k_scanC<<<SCANB, 256, 0, stream>>>(deg_cnt, cursor, bsum, offs, dis, dinv);
    k_csr<<<(EE + 255) / 256, 256, 0, stream>>>(erow, ecol, cursor, dis,
                                                csr_row, csr_nrm, EE);

    k_prep_h0<<<(MREAL * (K1P / 8) + 255) / 256, 256, 0, stream>>>(x, gl, bufA);
    k_prep_w<<<(256 * K1P + 255) / 256, 256, 0, stream>>>(W1, W1T, FF + GG, K1P);
    k_prep_w<<<(256 * 256 + 255) / 256, 256, 0, stream>>>(W2, W2T, 256, 256);
    k_prep_w<<<(256 * 256 + 255) / 256, 256, 0, stream>>>(W3, W3T, 256, 256);

    dim3 ggrid(MPAD / 128, 2);
    dim3 agrid(8 * AGG_GRP);

    // layer 1
    k_gemm<K1P><<<ggrid, 256, 0, stream>>>(bufA, W1T, bufC);
    k_agg<<<agrid, 256, 0, stream>>>(bufC, bufA, offs, csr_row, csr_nrm, dinv,
                                     b1, fcW + 0, g, 1);
    // layer 2
    k_gemm<256><<<ggrid, 256, 0, stream>>>(bufA, W2T, bufC);
    k_agg<<<agrid, 256, 0, stream>>>(bufC, bufA, offs, csr_row, csr_nrm, dinv,
                                     b2, fcW + 1, g, 1);
    // layer 3 (h3 not materialized; only fc contribution)
    k_gemm<256><<<ggrid, 256, 0, stream>>>(bufA, W3T, bufC);
    k_agg<<<agrid, 256, 0, stream>>>(bufC, bufA, offs, csr_row, csr_nrm, dinv,
                                     b3, fcW + 2, g, 0);

    k_lin1<<<NCHUNKS, 256, 0, stream>>>(g, fcb, l1W, zpart);
    k_lin1red<<<16, 256, 0, stream>>>(zpart, zacc);
    k_final<<<1, 512, 0, stream>>>(zacc, l1b, l2W, l2b, out);
}

// Round 5
// 477.907 us; speedup vs baseline: 1.6139x; 1.3130x over previous
//
#include <hip/hip_runtime.h>
#include <hip/hip_bf16.h>

using bf16 = __hip_bfloat16;
typedef short s16x8 __attribute__((ext_vector_type(8)));
typedef short s16x4 __attribute__((ext_vector_type(4)));
typedef float f32x4 __attribute__((ext_vector_type(4)));
typedef float f32x2 __attribute__((ext_vector_type(2)));

#define BSZ   8
#define NN    15135
#define FF    64
#define GG    73
#define HH    256
#define EE    242160
#define K1P   160                 // 137 padded to mult of 32
#define MREAL (BSZ * NN)          // 121080
#define MPAD  (946 * 128)         // 121088
#define HFC   512
#define NCHUNK 64
#define NCHUNKS ((NN + NCHUNK - 1) / NCHUNK)   // 237
#define SCANB  ((NN + 255) / 256)              // 60
// fp8 pre-scale: hw stored as e4m3(64*v); 1/64 folded into csr_norm & dinv
#define FP8_INV_SCALE 0.015625f

#define GLOAD_LDS16(gp, lp)                                                     \
    __builtin_amdgcn_global_load_lds(                                           \
        (const __attribute__((address_space(1))) void*)(gp),                    \
        (__attribute__((address_space(3))) void*)(lp), 16, 0, 0)

__device__ __forceinline__ unsigned char enc8(float v) {
    int p = __builtin_amdgcn_cvt_pk_fp8_f32(v, v, 0, false);
    return (unsigned char)(p & 0xff);
}

// ---------------------------------------------------------------- degree hist
__global__ void k_deg(const int* __restrict__ col, int* __restrict__ cnt, int e) {
    int i = blockIdx.x * blockDim.x + threadIdx.x;
    if (i < e) atomicAdd(&cnt[col[i]], 1);
}

// --------------------------------------------------------- scan phase A
__global__ __launch_bounds__(256)
void k_scanA(const int* __restrict__ cnt, int* __restrict__ cursor,
             int* __restrict__ bsum) {
    __shared__ int ws[4];
    int i = blockIdx.x * 256 + threadIdx.x;
    int tid = threadIdx.x, lane = tid & 63, wid = tid >> 6;
    int v = (i < NN) ? cnt[i] : 0;
    int s = v;
    #pragma unroll
    for (int off = 1; off < 64; off <<= 1) {
        int t = __shfl_up(s, off);
        if (lane >= off) s += t;
    }
    if (lane == 63) ws[wid] = s;
    __syncthreads();
    int pre = 0;
    #pragma unroll
    for (int w = 0; w < 4; ++w) pre += (w < wid) ? ws[w] : 0;
    int incl = pre + s;
    if (i < NN) cursor[i] = incl;
    if (tid == 255) bsum[blockIdx.x] = incl;
}

// --------------------------------------------------------- scan phase B
__global__ __launch_bounds__(64)
void k_scanB(int* __restrict__ bsum, int* __restrict__ offs) {
    int t = threadIdx.x;
    int v = (t < SCANB) ? bsum[t] : 0;
    int s = v;
    #pragma unroll
    for (int off = 1; off < 64; off <<= 1) {
        int x = __shfl_up(s, off);
        if (t >= off) s += x;
    }
    if (t < SCANB) bsum[t] = s - v;      // exclusive
    if (t == 63) offs[NN] = s;           // grand total
}

// --------------------------------------------------------- scan phase C
__global__ __launch_bounds__(256)
void k_scanC(const int* __restrict__ cnt, int* __restrict__ cursor,
             const int* __restrict__ bsum, int* __restrict__ offs,
             float* __restrict__ dis, float* __restrict__ dinv) {
    int i = blockIdx.x * 256 + threadIdx.x;
    if (i >= NN) return;
    int v = cnt[i];
    int excl = cursor[i] - v + bsum[blockIdx.x];
    offs[i] = excl;
    cursor[i] = excl;
    float d = (float)(v + 1);
    dis[i]  = rsqrtf(d);
    dinv[i] = (1.0f / d) * FP8_INV_SCALE;
}

// ---------------------------------------------------------------- CSR fill
// packed (row, norm) per edge -> one s_load_dwordx2 in k_agg
__global__ void k_csr(const int* __restrict__ row, const int* __restrict__ col,
                      int* __restrict__ cursor, const float* __restrict__ dis,
                      int2* __restrict__ cpack, int e) {
    int i = blockIdx.x * blockDim.x + threadIdx.x;
    if (i >= e) return;
    int r = row[i], c = col[i];
    int p = atomicAdd(&cursor[c], 1);
    cpack[p] = make_int2(r, __float_as_int(dis[r] * dis[c] * FP8_INV_SCALE));
}

// --------------------------------------------------------- h0 = [x | pe | 0]
__global__ void k_prep_h0(const float* __restrict__ x, const float* __restrict__ gl,
                          bf16* __restrict__ h0) {
    int idx = blockIdx.x * blockDim.x + threadIdx.x;
    if (idx >= MREAL * (K1P / 8)) return;
    int m = idx / (K1P / 8);
    int q = idx - m * (K1P / 8);
    int j0 = q * 8;
    int n = m % NN;
    s16x8 o;
    #pragma unroll
    for (int k = 0; k < 8; ++k) {
        int j = j0 + k;
        float val;
        if (j < FF) val = x[(size_t)m * FF + j];
        else if (j < FF + GG) val = gl[(size_t)n * GG + (j - FF)];
        else val = 0.f;
        o[k] = (short)__bfloat16_as_ushort(__float2bfloat16(val));
    }
    *(s16x8*)&h0[(size_t)m * K1P + j0] = o;
}

// ---------------------------------------------- W [K,256] f32 -> WT [256,Kp] bf16
__global__ void k_prep_w(const float* __restrict__ W, bf16* __restrict__ WT,
                         int K, int Kpad) {
    int idx = blockIdx.x * blockDim.x + threadIdx.x;
    if (idx >= 256 * Kpad) return;
    int nn = idx / Kpad, kk = idx - nn * Kpad;
    WT[idx] = __float2bfloat16(kk < K ? W[(size_t)kk * 256 + nn] : 0.f);
}

// ---------------------------------------------------------------- MFMA GEMM
// m97 structure: global_load_lds width=16, unpadded [128][32] LDS tiles.
// C (fp8, x64): [row][256] with row = b*NN+n  (per-batch planes, XCD-local agg)
#define BK 32
template <int K>
__global__ __launch_bounds__(256)
void k_gemm(const bf16* __restrict__ A, const bf16* __restrict__ BT,
            unsigned char* __restrict__ C) {
    __shared__ __align__(16) short As[128 * BK];
    __shared__ __align__(16) short Bs[128 * BK];
    const int tid  = threadIdx.x;
    const int bm   = blockIdx.x * 128;
    const int bn   = blockIdx.y * 128;
    const int lane = tid & 63, wave = tid >> 6;
    const int wm   = (wave >> 1) * 64, wn = (wave & 1) * 64;
    const int fr   = lane & 15, quad = lane >> 4;
    const int r    = tid >> 2;           // 0..63
    const int c    = (tid & 3) * 8;      // shorts: 0,8,16,24

    const bf16* Ap0 = A  + (size_t)(bm + r) * K + c;
    const bf16* Ap1 = Ap0 + (size_t)64 * K;
    const bf16* Bp0 = BT + (size_t)(bn + r) * K + c;
    const bf16* Bp1 = Bp0 + (size_t)64 * K;
    short* AsT0 = As + tid * 8;          // byte offset tid*16 (rows 0..63)
    short* AsT1 = As + 2048 + tid * 8;   // rows 64..127
    short* BsT0 = Bs + tid * 8;
    short* BsT1 = Bs + 2048 + tid * 8;

    f32x4 acc[4][4] = {};

    for (int k0 = 0; k0 < K; k0 += BK) {
        GLOAD_LDS16(Ap0 + k0, AsT0);
        GLOAD_LDS16(Ap1 + k0, AsT1);
        GLOAD_LDS16(Bp0 + k0, BsT0);
        GLOAD_LDS16(Bp1 + k0, BsT1);
        __syncthreads();
        s16x8 af[4], bfv[4];
        #pragma unroll
        for (int i = 0; i < 4; ++i)
            af[i] = *(const s16x8*)&As[(wm + i * 16 + fr) * BK + quad * 8];
        #pragma unroll
        for (int j = 0; j < 4; ++j)
            bfv[j] = *(const s16x8*)&Bs[(wn + j * 16 + fr) * BK + quad * 8];
        #pragma unroll
        for (int i = 0; i < 4; ++i)
            #pragma unroll
            for (int j = 0; j < 4; ++j)
                acc[i][j] = __builtin_amdgcn_mfma_f32_16x16x32_bf16(
                    af[i], bfv[j], acc[i][j], 0, 0, 0);
        __syncthreads();
    }

    // epilogue: store fp8 [row][256], value x64 (row = b*NN+n directly)
    #pragma unroll
    for (int i = 0; i < 4; ++i) {
        int rbase = bm + wm + i * 16 + quad * 4;
        #pragma unroll
        for (int rr = 0; rr < 4; ++rr) {
            int row = rbase + rr;
            if (row >= MREAL) continue;
            size_t co = (size_t)row * 256;
            #pragma unroll
            for (int j = 0; j < 4; ++j) {
                int colx = bn + wn + j * 16 + fr;
                C[co + colx] = enc8(acc[i][j][rr] * 64.f);
            }
        }
    }
}

// ------------------------------------------------------- aggregate + elu + fc
// hw fp8 [b*NN+n][256] (x64); hout bf16 [b*NN+n][256].
// Batch-partitioned for XCD L2 residency (blockIdx%8 -> XCD, plane 3.87MB<4MB).
// One node per wave. All per-edge metadata is wave-uniform -> scalar pipe:
// readfirstlane'd node id, s_load of packed (idx,norm), SGPR-based row loads.
// Row data: 64 lanes x dword (256 B). f32x2 accumulate (v_pk_fma_f32 path).
#define AGG_GRP 512                       // node groups per batch
#define AGG_STRIDE (AGG_GRP * 4)          // 2048 waves per batch
__global__ __launch_bounds__(256)
void k_agg(const unsigned char* __restrict__ hw, bf16* __restrict__ hout,
           const int* __restrict__ offs, const int2* __restrict__ cpack,
           const float* __restrict__ dinv,
           const float* __restrict__ bias, const float* __restrict__ fcW,
           float* __restrict__ g, int writeH) {
    const int b    = blockIdx.x & 7;
    const int grp  = blockIdx.x >> 3;          // 0..AGG_GRP-1
    const int wid  = threadIdx.x >> 6;         // 0..3
    const int lane = threadIdx.x & 63;
    const int wv   = grp * 4 + wid;            // 0..AGG_STRIDE-1
    const unsigned c4 = lane * 4;

    const unsigned char* hwb = hw + (size_t)b * NN * 256;

    float bias4[4], fw4[4];
    #pragma unroll
    for (int k = 0; k < 4; ++k) {
        bias4[k] = bias[c4 + k];
        fw4[k]   = fcW[3 * (c4 + k)];
    }

    for (int v0 = wv; v0 < NN; v0 += AGG_STRIDE) {
        const int v   = __builtin_amdgcn_readfirstlane(v0);
        const int beg = __builtin_amdgcn_readfirstlane(offs[v]);
        const int end = __builtin_amdgcn_readfirstlane(offs[v + 1]);
        const float di = dinv[v];
        f32x2 a01, a23;
        {
            unsigned q = *(const unsigned*)(hwb + (((unsigned)v) << 8) + c4);
            f32x2 t0 = __builtin_amdgcn_cvt_pk_f32_fp8(q, false);
            f32x2 t1 = __builtin_amdgcn_cvt_pk_f32_fp8(q, true);
            f32x2 dd = {di, di};
            a01 = dd * t0;
            a23 = dd * t1;
        }

        #define EDGE1(qv, mv) {                                            \
            f32x2 t0 = __builtin_amdgcn_cvt_pk_f32_fp8((qv), false);       \
            f32x2 t1 = __builtin_amdgcn_cvt_pk_f32_fp8((qv), true);        \
            f32x2 mm = {(mv), (mv)};                                       \
            a01 += mm * t0;                                                \
            a23 += mm * t1; }

        int e = beg;
        while (e + 8 <= end) {
            int2 ep[8];
            #pragma unroll
            for (int u = 0; u < 8; ++u) ep[u] = cpack[e + u];
            unsigned q[8];
            #pragma unroll
            for (int u = 0; u < 8; ++u)
                q[u] = *(const unsigned*)(hwb + (((unsigned)ep[u].x) << 8) + c4);
            #pragma unroll
            for (int u = 0; u < 8; ++u) EDGE1(q[u], __int_as_float(ep[u].y));
            e += 8;
        }
        if (e + 4 <= end) {
            int2 ep[4];
            #pragma unroll
            for (int u = 0; u < 4; ++u) ep[u] = cpack[e + u];
            unsigned q[4];
            #pragma unroll
            for (int u = 0; u < 4; ++u)
                q[u] = *(const unsigned*)(hwb + (((unsigned)ep[u].x) << 8) + c4);
            #pragma unroll
            for (int u = 0; u < 4; ++u) EDGE1(q[u], __int_as_float(ep[u].y));
            e += 4;
        }
        if (e + 2 <= end) {
            int2 ep0 = cpack[e], ep1 = cpack[e + 1];
            unsigned q0 = *(const unsigned*)(hwb + (((unsigned)ep0.x) << 8) + c4);
            unsigned q1 = *(const unsigned*)(hwb + (((unsigned)ep1.x) << 8) + c4);
            EDGE1(q0, __int_as_float(ep0.y));
            EDGE1(q1, __int_as_float(ep1.y));
            e += 2;
        }
        if (e < end) {
            int2 ep0 = cpack[e];
            unsigned q0 = *(const unsigned*)(hwb + (((unsigned)ep0.x) << 8) + c4);
            EDGE1(q0, __int_as_float(ep0.y));
        }
        #undef EDGE1

        float acc4[4] = {a01[0], a01[1], a23[0], a23[1]};
        float p = 0.f;
        s16x4 o4;
        #pragma unroll
        for (int k = 0; k < 4; ++k) {
            float hv = acc4[k] + bias4[k];
            hv = hv > 0.f ? hv : (__expf(hv) - 1.0f);
            o4[k] = (short)__bfloat16_as_ushort(__float2bfloat16(hv));
            p += hv * fw4[k];
        }
        if (writeH)
            *(s16x4*)&hout[((size_t)b * NN + v) * 256 + c4] = o4;

        #pragma unroll
        for (int off = 32; off; off >>= 1) p += __shfl_xor(p, off);
        if (lane == 0) g[(size_t)b * NN + v] += p;
    }
}

// ------------------------------------------------------------ lin1 partials
__global__ __launch_bounds__(256)
void k_lin1(const float* __restrict__ g, const float* __restrict__ fcb,
            const float* __restrict__ W, float* __restrict__ zpart) {
    const int ny = blockIdx.x;
    const int n0 = ny * NCHUNK;
    const int cnt = min(NCHUNK, NN - n0);
    const int tid = threadIdx.x;
    __shared__ float sg[8][NCHUNK];
    float fb = fcb[0];
    for (int idx = tid; idx < 8 * NCHUNK; idx += 256) {
        int b = idx / NCHUNK, nn = idx - b * NCHUNK;
        sg[b][nn] = (nn < cnt) ? (g[(size_t)b * NN + n0 + nn] + fb) : 0.f;
    }
    __syncthreads();
    float2 acc[8] = {};
    for (int nn = 0; nn < cnt; ++nn) {
        float2 w = *(const float2*)&W[(size_t)(n0 + nn) * HFC + tid * 2];
        #pragma unroll
        for (int b = 0; b < 8; ++b) {
            float gv = sg[b][nn];
            acc[b].x += gv * w.x;
            acc[b].y += gv * w.y;
        }
    }
    #pragma unroll
    for (int b = 0; b < 8; ++b)
        *(float2*)&zpart[(size_t)ny * 4096 + b * 512 + tid * 2] = acc[b];
}

__global__ __launch_bounds__(256)
void k_lin1red(const float* __restrict__ zpart, float* __restrict__ zacc) {
    int t = blockIdx.x * 256 + threadIdx.x;   // 0..4095
    float s = 0.f;
    for (int c = 0; c < NCHUNKS; ++c) s += zpart[(size_t)c * 4096 + t];
    zacc[t] = s;
}

// --------------------------------------------------- lin2 + log_softmax (tiny)
__global__ __launch_bounds__(512)
void k_final(const float* __restrict__ zacc, const float* __restrict__ l1b,
             const float* __restrict__ W2, const float* __restrict__ l2b,
             float* __restrict__ out) {
    __shared__ float r0[512], r1[512];
    int t = threadIdx.x;
    for (int b = 0; b < 8; ++b) {
        float zv = zacc[b * HFC + t] + l1b[t];
        zv = zv > 0.f ? zv : (__expf(zv) - 1.0f);
        r0[t] = zv * W2[t * 2 + 0];
        r1[t] = zv * W2[t * 2 + 1];
        __syncthreads();
        for (int s = 256; s; s >>= 1) {
            if (t < s) { r0[t] += r0[t + s]; r1[t] += r1[t + s]; }
            __syncthreads();
        }
        if (t == 0) {
            float o0 = r0[0] + l2b[0], o1 = r1[0] + l2b[1];
            float m = fmaxf(o0, o1);
            float lse = m + logf(expf(o0 - m) + expf(o1 - m));
            out[b * 2 + 0] = o0 - lse;
            out[b * 2 + 1] = o1 - lse;
        }
        __syncthreads();
    }
}

// ---------------------------------------------------------------- launcher
extern "C" void kernel_launch(void* const* d_in, const int* in_sizes, int n_in,
                              void* d_out, int out_size, void* d_ws, size_t ws_size,
                              hipStream_t stream) {
    const float* x    = (const float*)d_in[0];
    const int*   eidx = (const int*)d_in[2];      // [0..E) = row, [E..2E) = col
    const float* gl   = (const float*)d_in[3];
    const float* W1   = (const float*)d_in[4];
    const float* b1   = (const float*)d_in[5];
    const float* W2   = (const float*)d_in[6];
    const float* b2   = (const float*)d_in[7];
    const float* W3   = (const float*)d_in[8];
    const float* b3   = (const float*)d_in[9];
    const float* fcW  = (const float*)d_in[10];
    const float* fcb  = (const float*)d_in[11];
    const float* l1W  = (const float*)d_in[12];
    const float* l1b  = (const float*)d_in[13];
    const float* l2W  = (const float*)d_in[14];
    const float* l2b  = (const float*)d_in[15];
    float* out = (float*)d_out;

    size_t off = 0;
    auto alloc = [&](size_t bytes) {
        void* p = (char*)d_ws + off;
        off += (bytes + 255) & ~(size_t)255;
        return p;
    };
    bf16* bufA          = (bf16*)alloc((size_t)MPAD * 256 * 2);          // 62 MB
    unsigned char* bufC = (unsigned char*)alloc((size_t)MPAD * 256);     // 31 MB
    bf16* W1T      = (bf16*)alloc(256 * K1P * 2);
    bf16* W2T      = (bf16*)alloc(256 * 256 * 2);
    bf16* W3T      = (bf16*)alloc(256 * 256 * 2);
    int*  deg_cnt  = (int*)alloc(NN * 4);
    int*  offs     = (int*)alloc((NN + 1) * 4);
    int*  cursor   = (int*)alloc(NN * 4);
    int*  bsum     = (int*)alloc(SCANB * 4);
    float* dis     = (float*)alloc(NN * 4);
    float* dinv    = (float*)alloc(NN * 4);
    int2* cpack    = (int2*)alloc((size_t)EE * 8);
    float* g       = (float*)alloc((size_t)BSZ * NN * 4);

    // zpart/zacc alias bufC: dead after the last k_agg
    float* zpart = (float*)bufC;                              // 3.9 MB
    float* zacc  = (float*)(bufC + (8 << 20));                // 16 KB

    hipMemsetAsync(deg_cnt, 0, NN * 4, stream);
    hipMemsetAsync(g, 0, (size_t)BSZ * NN * 4, stream);

    const int* erow = eidx;
    const int* ecol = eidx + EE;

    k_deg<<<(EE + 255) / 256, 256, 0, stream>>>(ecol, deg_cnt, EE);
    k_scanA<<<SCANB, 256, 0, stream>>>(deg_cnt, cursor, bsum);
    k_scanB<<<1, 64, 0, stream>>>(bsum, offs);
    k_scanC<<<SCANB, 256, 0, stream>>>(deg_cnt, cursor, bsum, offs, dis, dinv);
    k_csr<<<(EE + 255) / 256, 256, 0, stream>>>(erow, ecol, cursor, dis,
                                                cpack, EE);

    k_prep_h0<<<(MREAL * (K1P / 8) + 255) / 256, 256, 0, stream>>>(x, gl, bufA);
    k_prep_w<<<(256 * K1P + 255) / 256, 256, 0, stream>>>(W1, W1T, FF + GG, K1P);
    k_prep_w<<<(256 * 256 + 255) / 256, 256, 0, stream>>>(W2, W2T, 256, 256);
    k_prep_w<<<(256 * 256 + 255) / 256, 256, 0, stream>>>(W3, W3T, 256, 256);

    dim3 ggrid(MPAD / 128, 2);
    dim3 agrid(8 * AGG_GRP);

    // layer 1
    k_gemm<K1P><<<ggrid, 256, 0, stream>>>(bufA, W1T, bufC);
    k_agg<<<agrid, 256, 0, stream>>>(bufC, bufA, offs, cpack, dinv,
                                     b1, fcW + 0, g, 1);
    // layer 2
    k_gemm<256><<<ggrid, 256, 0, stream>>>(bufA, W2T, bufC);
    k_agg<<<agrid, 256, 0, stream>>>(bufC, bufA, offs, cpack, dinv,
                                     b2, fcW + 1, g, 1);
    // layer 3 (h3 not materialized; only fc contribution)
    k_gemm<256><<<ggrid, 256, 0, stream>>>(bufA, W3T, bufC);
    k_agg<<<agrid, 256, 0, stream>>>(bufC, bufA, offs, cpack, dinv,
                                     b3, fcW + 2, g, 0);

    k_lin1<<<NCHUNKS, 256, 0, stream>>>(g, fcb, l1W, zpart);
    k_lin1red<<<16, 256, 0, stream>>>(zpart, zacc);
    k_final<<<1, 512, 0, stream>>>(zacc, l1b, l2W, l2b, out);
}

// Round 6
// 465.893 us; speedup vs baseline: 1.6555x; 1.0258x over previous
//
#include <hip/hip_runtime.h>
#include <hip/hip_bf16.h>

using bf16 = __hip_bfloat16;
typedef short s16x8 __attribute__((ext_vector_type(8)));
typedef short s16x4 __attribute__((ext_vector_type(4)));
typedef float f32x4 __attribute__((ext_vector_type(4)));
typedef float f32x2 __attribute__((ext_vector_type(2)));

#define BSZ   8
#define NN    15135
#define FF    64
#define GG    73
#define HH    256
#define EE    242160
#define K1P   160                 // 137 padded to mult of 32
#define MREAL (BSZ * NN)          // 121080
#define MPAD  (946 * 128)         // 121088
#define HFC   512
#define NCHUNK 64
#define NCHUNKS ((NN + NCHUNK - 1) / NCHUNK)   // 237
#define SCANB  ((NN + 255) / 256)              // 60
// fp8 pre-scale: hw stored as e4m3(64*v); 1/64 folded into csr_norm & dinv
#define FP8_INV_SCALE 0.015625f

#define GLOAD_LDS16(gp, lp)                                                     \
    __builtin_amdgcn_global_load_lds(                                           \
        (const __attribute__((address_space(1))) void*)(gp),                    \
        (__attribute__((address_space(3))) void*)(lp), 16, 0, 0)

// Column permutation applied to the 256-wide GEMM output space.
// Epilogue stores col c at byte position sigma(c) = (c&192) + 4*(c&15) + ((c>>4)&3);
// colmap(p) = sigma^-1(p): position p holds col (p&192) | ((p&3)<<4) | ((p>>2)&15).
// Aggregation is element-wise over rows, so a uniform column permutation commutes
// with it; consumers (bias/fcW lookups, W2T/W3T K-index) compensate via colmap.
__device__ __forceinline__ int colmap(int p) {
    return (p & 192) | ((p & 3) << 4) | ((p >> 2) & 15);
}

// ---------------------------------------------------------------- degree hist
__global__ void k_deg(const int* __restrict__ col, int* __restrict__ cnt, int e) {
    int i = blockIdx.x * blockDim.x + threadIdx.x;
    if (i < e) atomicAdd(&cnt[col[i]], 1);
}

// --------------------------------------------------------- scan phase A
__global__ __launch_bounds__(256)
void k_scanA(const int* __restrict__ cnt, int* __restrict__ cursor,
             int* __restrict__ bsum) {
    __shared__ int ws[4];
    int i = blockIdx.x * 256 + threadIdx.x;
    int tid = threadIdx.x, lane = tid & 63, wid = tid >> 6;
    int v = (i < NN) ? cnt[i] : 0;
    int s = v;
    #pragma unroll
    for (int off = 1; off < 64; off <<= 1) {
        int t = __shfl_up(s, off);
        if (lane >= off) s += t;
    }
    if (lane == 63) ws[wid] = s;
    __syncthreads();
    int pre = 0;
    #pragma unroll
    for (int w = 0; w < 4; ++w) pre += (w < wid) ? ws[w] : 0;
    int incl = pre + s;
    if (i < NN) cursor[i] = incl;
    if (tid == 255) bsum[blockIdx.x] = incl;
}

// --------------------------------------------------------- scan phase B
__global__ __launch_bounds__(64)
void k_scanB(int* __restrict__ bsum, int* __restrict__ offs) {
    int t = threadIdx.x;
    int v = (t < SCANB) ? bsum[t] : 0;
    int s = v;
    #pragma unroll
    for (int off = 1; off < 64; off <<= 1) {
        int x = __shfl_up(s, off);
        if (t >= off) s += x;
    }
    if (t < SCANB) bsum[t] = s - v;      // exclusive
    if (t == 63) offs[NN] = s;           // grand total
}

// --------------------------------------------------------- scan phase C
__global__ __launch_bounds__(256)
void k_scanC(const int* __restrict__ cnt, int* __restrict__ cursor,
             const int* __restrict__ bsum, int* __restrict__ offs,
             float* __restrict__ dis, float* __restrict__ dinv) {
    int i = blockIdx.x * 256 + threadIdx.x;
    if (i >= NN) return;
    int v = cnt[i];
    int excl = cursor[i] - v + bsum[blockIdx.x];
    offs[i] = excl;
    cursor[i] = excl;
    float d = (float)(v + 1);
    dis[i]  = rsqrtf(d);
    dinv[i] = (1.0f / d) * FP8_INV_SCALE;
}

// ---------------------------------------------------------------- CSR fill
// packed (row, norm) per edge -> one s_load_dwordx2 in k_agg
__global__ void k_csr(const int* __restrict__ row, const int* __restrict__ col,
                      int* __restrict__ cursor, const float* __restrict__ dis,
                      int2* __restrict__ cpack, int e) {
    int i = blockIdx.x * blockDim.x + threadIdx.x;
    if (i >= e) return;
    int r = row[i], c = col[i];
    int p = atomicAdd(&cursor[c], 1);
    cpack[p] = make_int2(r, __float_as_int(dis[r] * dis[c] * FP8_INV_SCALE));
}

// --------------------------------------------------------- h0 = [x | pe | 0]
__global__ void k_prep_h0(const float* __restrict__ x, const float* __restrict__ gl,
                          bf16* __restrict__ h0) {
    int idx = blockIdx.x * blockDim.x + threadIdx.x;
    if (idx >= MREAL * (K1P / 8)) return;
    int m = idx / (K1P / 8);
    int q = idx - m * (K1P / 8);
    int j0 = q * 8;
    int n = m % NN;
    s16x8 o;
    #pragma unroll
    for (int k = 0; k < 8; ++k) {
        int j = j0 + k;
        float val;
        if (j < FF) val = x[(size_t)m * FF + j];
        else if (j < FF + GG) val = gl[(size_t)n * GG + (j - FF)];
        else val = 0.f;
        o[k] = (short)__bfloat16_as_ushort(__float2bfloat16(val));
    }
    *(s16x8*)&h0[(size_t)m * K1P + j0] = o;
}

// ---------------------------------------------- W [K,256] f32 -> WT [256,Kp] bf16
// perm=1: K index passed through colmap (for layers whose A is in sigma-layout)
__global__ void k_prep_w(const float* __restrict__ W, bf16* __restrict__ WT,
                         int K, int Kpad, int perm) {
    int idx = blockIdx.x * blockDim.x + threadIdx.x;
    if (idx >= 256 * Kpad) return;
    int nn = idx / Kpad, kk = idx - nn * Kpad;
    int ks = perm ? colmap(kk) : kk;
    WT[idx] = __float2bfloat16(kk < K ? W[(size_t)ks * 256 + nn] : 0.f);
}

// ---------------------------------------------------------------- MFMA GEMM
// m97 structure: global_load_lds width=16, unpadded [128][32] LDS tiles.
// C (fp8, x64): [row][256] in sigma-layout: col c stored at byte position
// sigma(c) = (c&192) + 4*(c&15) + ((c>>4)&3). This makes each thread's 4
// j-values (fixed fr) byte-contiguous: 2x cvt_pk + 1 dword store per (i,rr)
// instead of 4 cvt + 4 scattered byte stores.
#define BK 32
template <int K>
__global__ __launch_bounds__(256)
void k_gemm(const bf16* __restrict__ A, const bf16* __restrict__ BT,
            unsigned char* __restrict__ C) {
    __shared__ __align__(16) short As[128 * BK];
    __shared__ __align__(16) short Bs[128 * BK];
    const int tid  = threadIdx.x;
    const int bm   = blockIdx.x * 128;
    const int bn   = blockIdx.y * 128;
    const int lane = tid & 63, wave = tid >> 6;
    const int wm   = (wave >> 1) * 64, wn = (wave & 1) * 64;
    const int fr   = lane & 15, quad = lane >> 4;
    const int r    = tid >> 2;           // 0..63
    const int c    = (tid & 3) * 8;      // shorts: 0,8,16,24

    const bf16* Ap0 = A  + (size_t)(bm + r) * K + c;
    const bf16* Ap1 = Ap0 + (size_t)64 * K;
    const bf16* Bp0 = BT + (size_t)(bn + r) * K + c;
    const bf16* Bp1 = Bp0 + (size_t)64 * K;
    short* AsT0 = As + tid * 8;          // byte offset tid*16 (rows 0..63)
    short* AsT1 = As + 2048 + tid * 8;   // rows 64..127
    short* BsT0 = Bs + tid * 8;
    short* BsT1 = Bs + 2048 + tid * 8;

    f32x4 acc[4][4] = {};

    for (int k0 = 0; k0 < K; k0 += BK) {
        GLOAD_LDS16(Ap0 + k0, AsT0);
        GLOAD_LDS16(Ap1 + k0, AsT1);
        GLOAD_LDS16(Bp0 + k0, BsT0);
        GLOAD_LDS16(Bp1 + k0, BsT1);
        __syncthreads();
        s16x8 af[4], bfv[4];
        #pragma unroll
        for (int i = 0; i < 4; ++i)
            af[i] = *(const s16x8*)&As[(wm + i * 16 + fr) * BK + quad * 8];
        #pragma unroll
        for (int j = 0; j < 4; ++j)
            bfv[j] = *(const s16x8*)&Bs[(wn + j * 16 + fr) * BK + quad * 8];
        #pragma unroll
        for (int i = 0; i < 4; ++i)
            #pragma unroll
            for (int j = 0; j < 4; ++j)
                acc[i][j] = __builtin_amdgcn_mfma_f32_16x16x32_bf16(
                    af[i], bfv[j], acc[i][j], 0, 0, 0);
        __syncthreads();
    }

    // epilogue: packed dword store per row (sigma-layout), value x64
    #pragma unroll
    for (int i = 0; i < 4; ++i) {
        int rbase = bm + wm + i * 16 + quad * 4;
        #pragma unroll
        for (int rr = 0; rr < 4; ++rr) {
            int row = rbase + rr;
            if (row >= MREAL) continue;
            unsigned wpack = (unsigned)__builtin_amdgcn_cvt_pk_fp8_f32(
                acc[i][0][rr] * 64.f, acc[i][1][rr] * 64.f, 0, false);
            wpack = (unsigned)__builtin_amdgcn_cvt_pk_fp8_f32(
                acc[i][2][rr] * 64.f, acc[i][3][rr] * 64.f, (int)wpack, true);
            *(unsigned*)&C[(size_t)row * 256 + bn + wn + fr * 4] = wpack;
        }
    }
}

// ------------------------------------------------------- aggregate + elu + fc
// hw fp8 [b*NN+n][256] (x64, sigma-layout); hout bf16 [b*NN+n][256] (sigma).
// Batch-partitioned for XCD L2 residency (blockIdx%8 -> XCD, plane 3.87MB<4MB).
// One node per wave; per-edge metadata wave-uniform -> scalar pipe.
// Position p holds col colmap(p); bias/fcW looked up through colmap at init.
#define AGG_GRP 512                       // node groups per batch
#define AGG_STRIDE (AGG_GRP * 4)          // 2048 waves per batch
__global__ __launch_bounds__(256)
void k_agg(const unsigned char* __restrict__ hw, bf16* __restrict__ hout,
           const int* __restrict__ offs, const int2* __restrict__ cpack,
           const float* __restrict__ dinv,
           const float* __restrict__ bias, const float* __restrict__ fcW,
           float* __restrict__ g, int writeH) {
    const int b    = blockIdx.x & 7;
    const int grp  = blockIdx.x >> 3;          // 0..AGG_GRP-1
    const int wid  = threadIdx.x >> 6;         // 0..3
    const int lane = threadIdx.x & 63;
    const int wv   = grp * 4 + wid;            // 0..AGG_STRIDE-1
    const unsigned c4 = lane * 4;

    const unsigned char* hwb = hw + (size_t)b * NN * 256;

    float bias4[4], fw4[4];
    #pragma unroll
    for (int k = 0; k < 4; ++k) {
        int cl = colmap((int)c4 + k);
        bias4[k] = bias[cl];
        fw4[k]   = fcW[3 * cl];
    }

    for (int v0 = wv; v0 < NN; v0 += AGG_STRIDE) {
        const int v   = __builtin_amdgcn_readfirstlane(v0);
        const int beg = __builtin_amdgcn_readfirstlane(offs[v]);
        const int end = __builtin_amdgcn_readfirstlane(offs[v + 1]);
        const float di = dinv[v];
        f32x2 a01, a23;
        {
            unsigned q = *(const unsigned*)(hwb + (((unsigned)v) << 8) + c4);
            f32x2 t0 = __builtin_amdgcn_cvt_pk_f32_fp8(q, false);
            f32x2 t1 = __builtin_amdgcn_cvt_pk_f32_fp8(q, true);
            f32x2 dd = {di, di};
            a01 = dd * t0;
            a23 = dd * t1;
        }

        #define EDGE1(qv, mv) {                                            \
            f32x2 t0 = __builtin_amdgcn_cvt_pk_f32_fp8((qv), false);       \
            f32x2 t1 = __builtin_amdgcn_cvt_pk_f32_fp8((qv), true);        \
            f32x2 mm = {(mv), (mv)};                                       \
            a01 += mm * t0;                                                \
            a23 += mm * t1; }

        int e = beg;
        while (e + 8 <= end) {
            int2 ep[8];
            #pragma unroll
            for (int u = 0; u < 8; ++u) ep[u] = cpack[e + u];
            unsigned q[8];
            #pragma unroll
            for (int u = 0; u < 8; ++u)
                q[u] = *(const unsigned*)(hwb + (((unsigned)ep[u].x) << 8) + c4);
            #pragma unroll
            for (int u = 0; u < 8; ++u) EDGE1(q[u], __int_as_float(ep[u].y));
            e += 8;
        }
        if (e + 4 <= end) {
            int2 ep[4];
            #pragma unroll
            for (int u = 0; u < 4; ++u) ep[u] = cpack[e + u];
            unsigned q[4];
            #pragma unroll
            for (int u = 0; u < 4; ++u)
                q[u] = *(const unsigned*)(hwb + (((unsigned)ep[u].x) << 8) + c4);
            #pragma unroll
            for (int u = 0; u < 4; ++u) EDGE1(q[u], __int_as_float(ep[u].y));
            e += 4;
        }
        if (e + 2 <= end) {
            int2 ep0 = cpack[e], ep1 = cpack[e + 1];
            unsigned q0 = *(const unsigned*)(hwb + (((unsigned)ep0.x) << 8) + c4);
            unsigned q1 = *(const unsigned*)(hwb + (((unsigned)ep1.x) << 8) + c4);
            EDGE1(q0, __int_as_float(ep0.y));
            EDGE1(q1, __int_as_float(ep1.y));
            e += 2;
        }
        if (e < end) {
            int2 ep0 = cpack[e];
            unsigned q0 = *(const unsigned*)(hwb + (((unsigned)ep0.x) << 8) + c4);
            EDGE1(q0, __int_as_float(ep0.y));
        }
        #undef EDGE1

        float acc4[4] = {a01[0], a01[1], a23[0], a23[1]};
        float p = 0.f;
        s16x4 o4;
        #pragma unroll
        for (int k = 0; k < 4; ++k) {
            float hv = acc4[k] + bias4[k];
            hv = hv > 0.f ? hv : (__expf(hv) - 1.0f);
            o4[k] = (short)__bfloat16_as_ushort(__float2bfloat16(hv));
            p += hv * fw4[k];
        }
        if (writeH)
            *(s16x4*)&hout[((size_t)b * NN + v) * 256 + c4] = o4;

        #pragma unroll
        for (int off = 32; off; off >>= 1) p += __shfl_xor(p, off);
        if (lane == 0) g[(size_t)b * NN + v] += p;
    }
}

// ------------------------------------------------------------ lin1 partials
__global__ __launch_bounds__(256)
void k_lin1(const float* __restrict__ g, const float* __restrict__ fcb,
            const float* __restrict__ W, float* __restrict__ zpart) {
    const int ny = blockIdx.x;
    const int n0 = ny * NCHUNK;
    const int cnt = min(NCHUNK, NN - n0);
    const int tid = threadIdx.x;
    __shared__ float sg[8][NCHUNK];
    float fb = fcb[0];
    for (int idx = tid; idx < 8 * NCHUNK; idx += 256) {
        int b = idx / NCHUNK, nn = idx - b * NCHUNK;
        sg[b][nn] = (nn < cnt) ? (g[(size_t)b * NN + n0 + nn] + fb) : 0.f;
    }
    __syncthreads();
    float2 acc[8] = {};
    for (int nn = 0; nn < cnt; ++nn) {
        float2 w = *(const float2*)&W[(size_t)(n0 + nn) * HFC + tid * 2];
        #pragma unroll
        for (int b = 0; b < 8; ++b) {
            float gv = sg[b][nn];
            acc[b].x += gv * w.x;
            acc[b].y += gv * w.y;
        }
    }
    #pragma unroll
    for (int b = 0; b < 8; ++b)
        *(float2*)&zpart[(size_t)ny * 4096 + b * 512 + tid * 2] = acc[b];
}

__global__ __launch_bounds__(256)
void k_lin1red(const float* __restrict__ zpart, float* __restrict__ zacc) {
    int t = blockIdx.x * 256 + threadIdx.x;   // 0..4095
    float s = 0.f;
    for (int c = 0; c < NCHUNKS; ++c) s += zpart[(size_t)c * 4096 + t];
    zacc[t] = s;
}

// --------------------------------------------------- lin2 + log_softmax (tiny)
__global__ __launch_bounds__(512)
void k_final(const float* __restrict__ zacc, const float* __restrict__ l1b,
             const float* __restrict__ W2, const float* __restrict__ l2b,
             float* __restrict__ out) {
    __shared__ float r0[512], r1[512];
    int t = threadIdx.x;
    for (int b = 0; b < 8; ++b) {
        float zv = zacc[b * HFC + t] + l1b[t];
        zv = zv > 0.f ? zv : (__expf(zv) - 1.0f);
        r0[t] = zv * W2[t * 2 + 0];
        r1[t] = zv * W2[t * 2 + 1];
        __syncthreads();
        for (int s = 256; s; s >>= 1) {
            if (t < s) { r0[t] += r0[t + s]; r1[t] += r1[t + s]; }
            __syncthreads();
        }
        if (t == 0) {
            float o0 = r0[0] + l2b[0], o1 = r1[0] + l2b[1];
            float m = fmaxf(o0, o1);
            float lse = m + logf(expf(o0 - m) + expf(o1 - m));
            out[b * 2 + 0] = o0 - lse;
            out[b * 2 + 1] = o1 - lse;
        }
        __syncthreads();
    }
}

// ---------------------------------------------------------------- launcher
extern "C" void kernel_launch(void* const* d_in, const int* in_sizes, int n_in,
                              void* d_out, int out_size, void* d_ws, size_t ws_size,
                              hipStream_t stream) {
    const float* x    = (const float*)d_in[0];
    const int*   eidx = (const int*)d_in[2];      // [0..E) = row, [E..2E) = col
    const float* gl   = (const float*)d_in[3];
    const float* W1   = (const float*)d_in[4];
    const float* b1   = (const float*)d_in[5];
    const float* W2   = (const float*)d_in[6];
    const float* b2   = (const float*)d_in[7];
    const float* W3   = (const float*)d_in[8];
    const float* b3   = (const float*)d_in[9];
    const float* fcW  = (const float*)d_in[10];
    const float* fcb  = (const float*)d_in[11];
    const float* l1W  = (const float*)d_in[12];
    const float* l1b  = (const float*)d_in[13];
    const float* l2W  = (const float*)d_in[14];
    const float* l2b  = (const float*)d_in[15];
    float* out = (float*)d_out;

    size_t off = 0;
    auto alloc = [&](size_t bytes) {
        void* p = (char*)d_ws + off;
        off += (bytes + 255) & ~(size_t)255;
        return p;
    };
    bf16* bufA          = (bf16*)alloc((size_t)MPAD * 256 * 2);          // 62 MB
    unsigned char* bufC = (unsigned char*)alloc((size_t)MPAD * 256);     // 31 MB
    bf16* W1T      = (bf16*)alloc(256 * K1P * 2);
    bf16* W2T      = (bf16*)alloc(256 * 256 * 2);
    bf16* W3T      = (bf16*)alloc(256 * 256 * 2);
    int*  deg_cnt  = (int*)alloc(NN * 4);
    int*  offs     = (int*)alloc((NN + 1) * 4);
    int*  cursor   = (int*)alloc(NN * 4);
    int*  bsum     = (int*)alloc(SCANB * 4);
    float* dis     = (float*)alloc(NN * 4);
    float* dinv    = (float*)alloc(NN * 4);
    int2* cpack    = (int2*)alloc((size_t)EE * 8);
    float* g       = (float*)alloc((size_t)BSZ * NN * 4);

    // zpart/zacc alias bufC: dead after the last k_agg
    float* zpart = (float*)bufC;                              // 3.9 MB
    float* zacc  = (float*)(bufC + (8 << 20));                // 16 KB

    hipMemsetAsync(deg_cnt, 0, NN * 4, stream);
    hipMemsetAsync(g, 0, (size_t)BSZ * NN * 4, stream);

    const int* erow = eidx;
    const int* ecol = eidx + EE;

    k_deg<<<(EE + 255) / 256, 256, 0, stream>>>(ecol, deg_cnt, EE);
    k_scanA<<<SCANB, 256, 0, stream>>>(deg_cnt, cursor, bsum);
    k_scanB<<<1, 64, 0, stream>>>(bsum, offs);
    k_scanC<<<SCANB, 256, 0, stream>>>(deg_cnt, cursor, bsum, offs, dis, dinv);
    k_csr<<<(EE + 255) / 256, 256, 0, stream>>>(erow, ecol, cursor, dis,
                                                cpack, EE);

    k_prep_h0<<<(MREAL * (K1P / 8) + 255) / 256, 256, 0, stream>>>(x, gl, bufA);
    k_prep_w<<<(256 * K1P + 255) / 256, 256, 0, stream>>>(W1, W1T, FF + GG, K1P, 0);
    k_prep_w<<<(256 * 256 + 255) / 256, 256, 0, stream>>>(W2, W2T, 256, 256, 1);
    k_prep_w<<<(256 * 256 + 255) / 256, 256, 0, stream>>>(W3, W3T, 256, 256, 1);

    dim3 ggrid(MPAD / 128, 2);
    dim3 agrid(8 * AGG_GRP);

    // layer 1
    k_gemm<K1P><<<ggrid, 256, 0, stream>>>(bufA, W1T, bufC);
    k_agg<<<agrid, 256, 0, stream>>>(bufC, bufA, offs, cpack, dinv,
                                     b1, fcW + 0, g, 1);
    // layer 2
    k_gemm<256><<<ggrid, 256, 0, stream>>>(bufA, W2T, bufC);
    k_agg<<<agrid, 256, 0, stream>>>(bufC, bufA, offs, cpack, dinv,
                                     b2, fcW + 1, g, 1);
    // layer 3 (h3 not materialized; only fc contribution)
    k_gemm<256><<<ggrid, 256, 0, stream>>>(bufA, W3T, bufC);
    k_agg<<<agrid, 256, 0, stream>>>(bufC, bufA, offs, cpack, dinv,
                                     b3, fcW + 2, g, 0);

    k_lin1<<<NCHUNKS, 256, 0, stream>>>(g, fcb, l1W, zpart);
    k_lin1red<<<16, 256, 0, stream>>>(zpart, zacc);
    k_final<<<1, 512, 0, stream>>>(zacc, l1b, l2W, l2b, out);
}

// Round 7
// 459.758 us; speedup vs baseline: 1.6776x; 1.0133x over previous
//
#include <hip/hip_runtime.h>
#include <hip/hip_bf16.h>

using bf16 = __hip_bfloat16;
typedef short s16x8 __attribute__((ext_vector_type(8)));
typedef short s16x4 __attribute__((ext_vector_type(4)));
typedef float f32x4 __attribute__((ext_vector_type(4)));
typedef float f32x2 __attribute__((ext_vector_type(2)));

#define BSZ   8
#define NN    15135
#define FF    64
#define GG    73
#define HH    256
#define EE    242160
#define K1P   160                 // 137 padded to mult of 32
#define MREAL (BSZ * NN)          // 121080
#define MPAD  (946 * 128)         // 121088
#define HFC   512
#define NCHUNK 64
#define NCHUNKS ((NN + NCHUNK - 1) / NCHUNK)   // 237
#define SCANB  ((NN + 255) / 256)              // 60
// fp8 pre-scale: hw stored as e4m3(64*v); x64 folded into WT, 1/64 into csr_norm & dinv
#define FP8_INV_SCALE 0.015625f

#define GLOAD_LDS16(gp, lp)                                                     \
    __builtin_amdgcn_global_load_lds(                                           \
        (const __attribute__((address_space(1))) void*)(gp),                    \
        (__attribute__((address_space(3))) void*)(lp), 16, 0, 0)

// Column permutation applied to the 256-wide GEMM output space.
// Epilogue stores col c at byte position sigma(c) = (c&192) + 4*(c&15) + ((c>>4)&3);
// colmap(p) = sigma^-1(p): position p holds col (p&192) | ((p&3)<<4) | ((p>>2)&15).
// Aggregation is element-wise over rows, so a uniform column permutation commutes
// with it; consumers (bias/fcW lookups, W2T/W3T K-index) compensate via colmap.
__device__ __forceinline__ int colmap(int p) {
    return (p & 192) | ((p & 3) << 4) | ((p >> 2) & 15);
}

// ---------------------------------------------------------------- degree hist
__global__ void k_deg(const int* __restrict__ col, int* __restrict__ cnt, int e) {
    int i = blockIdx.x * blockDim.x + threadIdx.x;
    if (i < e) atomicAdd(&cnt[col[i]], 1);
}

// --------------------------------------------------------- scan phase A
__global__ __launch_bounds__(256)
void k_scanA(const int* __restrict__ cnt, int* __restrict__ cursor,
             int* __restrict__ bsum) {
    __shared__ int ws[4];
    int i = blockIdx.x * 256 + threadIdx.x;
    int tid = threadIdx.x, lane = tid & 63, wid = tid >> 6;
    int v = (i < NN) ? cnt[i] : 0;
    int s = v;
    #pragma unroll
    for (int off = 1; off < 64; off <<= 1) {
        int t = __shfl_up(s, off);
        if (lane >= off) s += t;
    }
    if (lane == 63) ws[wid] = s;
    __syncthreads();
    int pre = 0;
    #pragma unroll
    for (int w = 0; w < 4; ++w) pre += (w < wid) ? ws[w] : 0;
    int incl = pre + s;
    if (i < NN) cursor[i] = incl;
    if (tid == 255) bsum[blockIdx.x] = incl;
}

// --------------------------------------------------------- scan phase B
__global__ __launch_bounds__(64)
void k_scanB(int* __restrict__ bsum, int* __restrict__ offs) {
    int t = threadIdx.x;
    int v = (t < SCANB) ? bsum[t] : 0;
    int s = v;
    #pragma unroll
    for (int off = 1; off < 64; off <<= 1) {
        int x = __shfl_up(s, off);
        if (t >= off) s += x;
    }
    if (t < SCANB) bsum[t] = s - v;      // exclusive
    if (t == 63) offs[NN] = s;           // grand total
}

// --------------------------------------------------------- scan phase C
__global__ __launch_bounds__(256)
void k_scanC(const int* __restrict__ cnt, int* __restrict__ cursor,
             const int* __restrict__ bsum, int* __restrict__ offs,
             float* __restrict__ dis, float* __restrict__ dinv) {
    int i = blockIdx.x * 256 + threadIdx.x;
    if (i >= NN) return;
    int v = cnt[i];
    int excl = cursor[i] - v + bsum[blockIdx.x];
    offs[i] = excl;
    cursor[i] = excl;
    float d = (float)(v + 1);
    dis[i]  = rsqrtf(d);
    dinv[i] = (1.0f / d) * FP8_INV_SCALE;
}

// ---------------------------------------------------------------- CSR fill
// packed (row, norm) per edge -> one s_load_dwordx2 in k_agg
__global__ void k_csr(const int* __restrict__ row, const int* __restrict__ col,
                      int* __restrict__ cursor, const float* __restrict__ dis,
                      int2* __restrict__ cpack, int e) {
    int i = blockIdx.x * blockDim.x + threadIdx.x;
    if (i >= e) return;
    int r = row[i], c = col[i];
    int p = atomicAdd(&cursor[c], 1);
    cpack[p] = make_int2(r, __float_as_int(dis[r] * dis[c] * FP8_INV_SCALE));
}

// --------------------------------------------------------- h0 = [x | pe | 0]
__global__ void k_prep_h0(const float* __restrict__ x, const float* __restrict__ gl,
                          bf16* __restrict__ h0) {
    int idx = blockIdx.x * blockDim.x + threadIdx.x;
    if (idx >= MREAL * (K1P / 8)) return;
    int m = idx / (K1P / 8);
    int q = idx - m * (K1P / 8);
    int j0 = q * 8;
    int n = m % NN;
    s16x8 o;
    #pragma unroll
    for (int k = 0; k < 8; ++k) {
        int j = j0 + k;
        float val;
        if (j < FF) val = x[(size_t)m * FF + j];
        else if (j < FF + GG) val = gl[(size_t)n * GG + (j - FF)];
        else val = 0.f;
        o[k] = (short)__bfloat16_as_ushort(__float2bfloat16(val));
    }
    *(s16x8*)&h0[(size_t)m * K1P + j0] = o;
}

// ----------------------- W [K,256] f32 -> WT [256,Kp] bf16, x64 scale folded
// W2T/W3T K-index passed through colmap (their A is in sigma-layout).
// Single fused kernel for all three weight preps.
__global__ void k_prep_w3(const float* __restrict__ W1, const float* __restrict__ W2,
                          const float* __restrict__ W3, bf16* __restrict__ W1T,
                          bf16* __restrict__ W2T, bf16* __restrict__ W3T) {
    int idx = blockIdx.x * blockDim.x + threadIdx.x;
    if (idx < 256 * K1P) {
        int nn = idx / K1P, kk = idx - nn * K1P;
        W1T[idx] = __float2bfloat16(
            kk < FF + GG ? 64.f * W1[(size_t)kk * 256 + nn] : 0.f);
    } else if (idx < 256 * K1P + 65536) {
        int j = idx - 256 * K1P;
        int nn = j >> 8, kk = j & 255;
        W2T[j] = __float2bfloat16(64.f * W2[(size_t)colmap(kk) * 256 + nn]);
    } else if (idx < 256 * K1P + 2 * 65536) {
        int j = idx - 256 * K1P - 65536;
        int nn = j >> 8, kk = j & 255;
        W3T[j] = __float2bfloat16(64.f * W3[(size_t)colmap(kk) * 256 + nn]);
    }
}

// ---------------------------------------------------------------- MFMA GEMM
// BM=64 x BN=256: A read exactly once (was twice with the 128x128 grid.y=2
// tiling); B (128KB) is L2-resident per XCD so per-block re-reads are cheap.
// 256 threads = 4 waves side by side, each computing 64 rows x 64 cols.
// C (fp8, x64 via pre-scaled WT): [row][256] sigma-layout, packed dword stores.
#define BK 32
template <int K>
__global__ __launch_bounds__(256)
void k_gemm(const bf16* __restrict__ A, const bf16* __restrict__ BT,
            unsigned char* __restrict__ C) {
    __shared__ __align__(16) short As[64 * BK];      // 4 KB
    __shared__ __align__(16) short Bs[256 * BK];     // 16 KB
    const int tid  = threadIdx.x;
    const int bm   = blockIdx.x * 64;
    const int lane = tid & 63, wave = tid >> 6;
    const int wn   = wave * 64;
    const int fr   = lane & 15, quad = lane >> 4;
    const int r    = tid >> 2;           // 0..63
    const int c    = (tid & 3) * 8;      // shorts: 0,8,16,24

    const bf16* Ap = A  + (size_t)(bm + r) * K + c;
    const bf16* Bp = BT + (size_t)r * K + c;        // rows 0..63 (quarter 0)
    short* AsT = As + tid * 8;                      // byte offset tid*16
    short* BsT = Bs + tid * 8;

    f32x4 acc[4][4] = {};

    for (int k0 = 0; k0 < K; k0 += BK) {
        GLOAD_LDS16(Ap + k0, AsT);
        #pragma unroll
        for (int q = 0; q < 4; ++q)
            GLOAD_LDS16(Bp + (size_t)(q * 64) * K + k0, BsT + q * 64 * BK);
        __syncthreads();
        s16x8 af[4], bfv[4];
        #pragma unroll
        for (int i = 0; i < 4; ++i)
            af[i] = *(const s16x8*)&As[(i * 16 + fr) * BK + quad * 8];
        #pragma unroll
        for (int j = 0; j < 4; ++j)
            bfv[j] = *(const s16x8*)&Bs[(wn + j * 16 + fr) * BK + quad * 8];
        #pragma unroll
        for (int i = 0; i < 4; ++i)
            #pragma unroll
            for (int j = 0; j < 4; ++j)
                acc[i][j] = __builtin_amdgcn_mfma_f32_16x16x32_bf16(
                    af[i], bfv[j], acc[i][j], 0, 0, 0);
        __syncthreads();
    }

    // epilogue: packed dword store per row (sigma-layout); x64 already in WT
    #pragma unroll
    for (int i = 0; i < 4; ++i) {
        int rbase = bm + i * 16 + quad * 4;
        #pragma unroll
        for (int rr = 0; rr < 4; ++rr) {
            int row = rbase + rr;
            if (row >= MREAL) continue;
            unsigned wpack = (unsigned)__builtin_amdgcn_cvt_pk_fp8_f32(
                acc[i][0][rr], acc[i][1][rr], 0, false);
            wpack = (unsigned)__builtin_amdgcn_cvt_pk_fp8_f32(
                acc[i][2][rr], acc[i][3][rr], (int)wpack, true);
            *(unsigned*)&C[(size_t)row * 256 + wn + fr * 4] = wpack;
        }
    }
}

// ------------------------------------------------------- aggregate + elu + fc
// hw fp8 [b*NN+n][256] (x64, sigma-layout); hout bf16 [b*NN+n][256] (sigma).
// Batch-partitioned for XCD L2 residency (blockIdx%8 -> XCD, plane 3.87MB<4MB).
// One node per wave; per-edge metadata wave-uniform -> scalar pipe.
// Position p holds col colmap(p); bias/fcW looked up through colmap at init.
#define AGG_GRP 512                       // node groups per batch
#define AGG_STRIDE (AGG_GRP * 4)          // 2048 waves per batch
__global__ __launch_bounds__(256)
void k_agg(const unsigned char* __restrict__ hw, bf16* __restrict__ hout,
           const int* __restrict__ offs, const int2* __restrict__ cpack,
           const float* __restrict__ dinv,
           const float* __restrict__ bias, const float* __restrict__ fcW,
           float* __restrict__ g, int writeH) {
    const int b    = blockIdx.x & 7;
    const int grp  = blockIdx.x >> 3;          // 0..AGG_GRP-1
    const int wid  = threadIdx.x >> 6;         // 0..3
    const int lane = threadIdx.x & 63;
    const int wv   = grp * 4 + wid;            // 0..AGG_STRIDE-1
    const unsigned c4 = lane * 4;

    const unsigned char* hwb = hw + (size_t)b * NN * 256;

    float bias4[4], fw4[4];
    #pragma unroll
    for (int k = 0; k < 4; ++k) {
        int cl = colmap((int)c4 + k);
        bias4[k] = bias[cl];
        fw4[k]   = fcW[3 * cl];
    }

    for (int v0 = wv; v0 < NN; v0 += AGG_STRIDE) {
        const int v   = __builtin_amdgcn_readfirstlane(v0);
        const int beg = __builtin_amdgcn_readfirstlane(offs[v]);
        const int end = __builtin_amdgcn_readfirstlane(offs[v + 1]);
        const float di = dinv[v];
        f32x2 a01, a23;
        {
            unsigned q = *(const unsigned*)(hwb + (((unsigned)v) << 8) + c4);
            f32x2 t0 = __builtin_amdgcn_cvt_pk_f32_fp8(q, false);
            f32x2 t1 = __builtin_amdgcn_cvt_pk_f32_fp8(q, true);
            f32x2 dd = {di, di};
            a01 = dd * t0;
            a23 = dd * t1;
        }

        #define EDGE1(qv, mv) {                                            \
            f32x2 t0 = __builtin_amdgcn_cvt_pk_f32_fp8((qv), false);       \
            f32x2 t1 = __builtin_amdgcn_cvt_pk_f32_fp8((qv), true);        \
            f32x2 mm = {(mv), (mv)};                                       \
            a01 += mm * t0;                                                \
            a23 += mm * t1; }

        int e = beg;
        while (e + 8 <= end) {
            int2 ep[8];
            #pragma unroll
            for (int u = 0; u < 8; ++u) ep[u] = cpack[e + u];
            unsigned q[8];
            #pragma unroll
            for (int u = 0; u < 8; ++u)
                q[u] = *(const unsigned*)(hwb + (((unsigned)ep[u].x) << 8) + c4);
            #pragma unroll
            for (int u = 0; u < 8; ++u) EDGE1(q[u], __int_as_float(ep[u].y));
            e += 8;
        }
        if (e + 4 <= end) {
            int2 ep[4];
            #pragma unroll
            for (int u = 0; u < 4; ++u) ep[u] = cpack[e + u];
            unsigned q[4];
            #pragma unroll
            for (int u = 0; u < 4; ++u)
                q[u] = *(const unsigned*)(hwb + (((unsigned)ep[u].x) << 8) + c4);
            #pragma unroll
            for (int u = 0; u < 4; ++u) EDGE1(q[u], __int_as_float(ep[u].y));
            e += 4;
        }
        if (e + 2 <= end) {
            int2 ep0 = cpack[e], ep1 = cpack[e + 1];
            unsigned q0 = *(const unsigned*)(hwb + (((unsigned)ep0.x) << 8) + c4);
            unsigned q1 = *(const unsigned*)(hwb + (((unsigned)ep1.x) << 8) + c4);
            EDGE1(q0, __int_as_float(ep0.y));
            EDGE1(q1, __int_as_float(ep1.y));
            e += 2;
        }
        if (e < end) {
            int2 ep0 = cpack[e];
            unsigned q0 = *(const unsigned*)(hwb + (((unsigned)ep0.x) << 8) + c4);
            EDGE1(q0, __int_as_float(ep0.y));
        }
        #undef EDGE1

        float acc4[4] = {a01[0], a01[1], a23[0], a23[1]};
        float p = 0.f;
        s16x4 o4;
        #pragma unroll
        for (int k = 0; k < 4; ++k) {
            float hv = acc4[k] + bias4[k];
            hv = hv > 0.f ? hv : (__expf(hv) - 1.0f);
            o4[k] = (short)__bfloat16_as_ushort(__float2bfloat16(hv));
            p += hv * fw4[k];
        }
        if (writeH)
            *(s16x4*)&hout[((size_t)b * NN + v) * 256 + c4] = o4;

        #pragma unroll
        for (int off = 32; off; off >>= 1) p += __shfl_xor(p, off);
        if (lane == 0) g[(size_t)b * NN + v] += p;
    }
}

// ------------------------------------------------------------ lin1 partials
__global__ __launch_bounds__(256)
void k_lin1(const float* __restrict__ g, const float* __restrict__ fcb,
            const float* __restrict__ W, float* __restrict__ zpart) {
    const int ny = blockIdx.x;
    const int n0 = ny * NCHUNK;
    const int cnt = min(NCHUNK, NN - n0);
    const int tid = threadIdx.x;
    __shared__ float sg[8][NCHUNK];
    float fb = fcb[0];
    for (int idx = tid; idx < 8 * NCHUNK; idx += 256) {
        int b = idx / NCHUNK, nn = idx - b * NCHUNK;
        sg[b][nn] = (nn < cnt) ? (g[(size_t)b * NN + n0 + nn] + fb) : 0.f;
    }
    __syncthreads();
    float2 acc[8] = {};
    for (int nn = 0; nn < cnt; ++nn) {
        float2 w = *(const float2*)&W[(size_t)(n0 + nn) * HFC + tid * 2];
        #pragma unroll
        for (int b = 0; b < 8; ++b) {
            float gv = sg[b][nn];
            acc[b].x += gv * w.x;
            acc[b].y += gv * w.y;
        }
    }
    #pragma unroll
    for (int b = 0; b < 8; ++b)
        *(float2*)&zpart[(size_t)ny * 4096 + b * 512 + tid * 2] = acc[b];
}

__global__ __launch_bounds__(256)
void k_lin1red(const float* __restrict__ zpart, float* __restrict__ zacc) {
    int t = blockIdx.x * 256 + threadIdx.x;   // 0..4095
    float s = 0.f;
    for (int c = 0; c < NCHUNKS; ++c) s += zpart[(size_t)c * 4096 + t];
    zacc[t] = s;
}

// --------------------------------------------------- lin2 + log_softmax (tiny)
__global__ __launch_bounds__(512)
void k_final(const float* __restrict__ zacc, const float* __restrict__ l1b,
             const float* __restrict__ W2, const float* __restrict__ l2b,
             float* __restrict__ out) {
    __shared__ float r0[512], r1[512];
    int t = threadIdx.x;
    for (int b = 0; b < 8; ++b) {
        float zv = zacc[b * HFC + t] + l1b[t];
        zv = zv > 0.f ? zv : (__expf(zv) - 1.0f);
        r0[t] = zv * W2[t * 2 + 0];
        r1[t] = zv * W2[t * 2 + 1];
        __syncthreads();
        for (int s = 256; s; s >>= 1) {
            if (t < s) { r0[t] += r0[t + s]; r1[t] += r1[t + s]; }
            __syncthreads();
        }
        if (t == 0) {
            float o0 = r0[0] + l2b[0], o1 = r1[0] + l2b[1];
            float m = fmaxf(o0, o1);
            float lse = m + logf(expf(o0 - m) + expf(o1 - m));
            out[b * 2 + 0] = o0 - lse;
            out[b * 2 + 1] = o1 - lse;
        }
        __syncthreads();
    }
}

// ---------------------------------------------------------------- launcher
extern "C" void kernel_launch(void* const* d_in, const int* in_sizes, int n_in,
                              void* d_out, int out_size, void* d_ws, size_t ws_size,
                              hipStream_t stream) {
    const float* x    = (const float*)d_in[0];
    const int*   eidx = (const int*)d_in[2];      // [0..E) = row, [E..2E) = col
    const float* gl   = (const float*)d_in[3];
    const float* W1   = (const float*)d_in[4];
    const float* b1   = (const float*)d_in[5];
    const float* W2   = (const float*)d_in[6];
    const float* b2   = (const float*)d_in[7];
    const float* W3   = (const float*)d_in[8];
    const float* b3   = (const float*)d_in[9];
    const float* fcW  = (const float*)d_in[10];
    const float* fcb  = (const float*)d_in[11];
    const float* l1W  = (const float*)d_in[12];
    const float* l1b  = (const float*)d_in[13];
    const float* l2W  = (const float*)d_in[14];
    const float* l2b  = (const float*)d_in[15];
    float* out = (float*)d_out;

    size_t off = 0;
    auto alloc = [&](size_t bytes) {
        void* p = (char*)d_ws + off;
        off += (bytes + 255) & ~(size_t)255;
        return p;
    };
    bf16* bufA          = (bf16*)alloc((size_t)MPAD * 256 * 2);          // 62 MB
    unsigned char* bufC = (unsigned char*)alloc((size_t)MPAD * 256);     // 31 MB
    bf16* W1T      = (bf16*)alloc(256 * K1P * 2);
    bf16* W2T      = (bf16*)alloc(256 * 256 * 2);
    bf16* W3T      = (bf16*)alloc(256 * 256 * 2);
    int*  deg_cnt  = (int*)alloc(NN * 4);
    int*  offs     = (int*)alloc((NN + 1) * 4);
    int*  cursor   = (int*)alloc(NN * 4);
    int*  bsum     = (int*)alloc(SCANB * 4);
    float* dis     = (float*)alloc(NN * 4);
    float* dinv    = (float*)alloc(NN * 4);
    int2* cpack    = (int2*)alloc((size_t)EE * 8);
    float* g       = (float*)alloc((size_t)BSZ * NN * 4);

    // zpart/zacc alias bufC: dead after the last k_agg
    float* zpart = (float*)bufC;                              // 3.9 MB
    float* zacc  = (float*)(bufC + (8 << 20));                // 16 KB

    hipMemsetAsync(deg_cnt, 0, NN * 4, stream);
    hipMemsetAsync(g, 0, (size_t)BSZ * NN * 4, stream);

    const int* erow = eidx;
    const int* ecol = eidx + EE;

    k_deg<<<(EE + 255) / 256, 256, 0, stream>>>(ecol, deg_cnt, EE);
    k_scanA<<<SCANB, 256, 0, stream>>>(deg_cnt, cursor, bsum);
    k_scanB<<<1, 64, 0, stream>>>(bsum, offs);
    k_scanC<<<SCANB, 256, 0, stream>>>(deg_cnt, cursor, bsum, offs, dis, dinv);
    k_csr<<<(EE + 255) / 256, 256, 0, stream>>>(erow, ecol, cursor, dis,
                                                cpack, EE);

    k_prep_h0<<<(MREAL * (K1P / 8) + 255) / 256, 256, 0, stream>>>(x, gl, bufA);
    k_prep_w3<<<(256 * K1P + 2 * 65536 + 255) / 256, 256, 0, stream>>>(
        W1, W2, W3, W1T, W2T, W3T);

    dim3 ggrid(MPAD / 64);
    dim3 agrid(8 * AGG_GRP);

    // layer 1
    k_gemm<K1P><<<ggrid, 256, 0, stream>>>(bufA, W1T, bufC);
    k_agg<<<agrid, 256, 0, stream>>>(bufC, bufA, offs, cpack, dinv,
                                     b1, fcW + 0, g, 1);
    // layer 2
    k_gemm<256><<<ggrid, 256, 0, stream>>>(bufA, W2T, bufC);
    k_agg<<<agrid, 256, 0, stream>>>(bufC, bufA, offs, cpack, dinv,
                                     b2, fcW + 1, g, 1);
    // layer 3 (h3 not materialized; only fc contribution)
    k_gemm<256><<<ggrid, 256, 0, stream>>>(bufA, W3T, bufC);
    k_agg<<<agrid, 256, 0, stream>>>(bufC, bufA, offs, cpack, dinv,
                                     b3, fcW + 2, g, 0);

    k_lin1<<<NCHUNKS, 256, 0, stream>>>(g, fcb, l1W, zpart);
    k_lin1red<<<16, 256, 0, stream>>>(zpart, zacc);
    k_final<<<1, 512, 0, stream>>>(zacc, l1b, l2W, l2b, out);
}